// Round 10
// baseline (614.452 us; speedup 1.0000x reference)
//
#include <hip/hip_runtime.h>
#include <math.h>

// ---------------- problem constants ----------------
#define NPTS 100000
#define KNB  16
#define NK   1600000            // NPTS*KNB

// output layout (float offsets)
#define OUT_XK   6400000        // after x_out [N,64]
#define OUT_KNN  108800000      // after xk [N,16,64]
#define OUT_PR   110400000      // after knn [N,16]

// workspace layout (float offsets)
#define WS_BNP_RAW 0            // 6   (sum3, ssq3)
#define WS_BN2_RAW 134          // 16  (sum8, ssq8)
#define WS_BNP_SS  160          // 6   (scale3, shift3)
#define WS_WS2     166          // 48  (16x3 shrunk lp_w2)
#define WS_WSB     214          // 16  (shrunk lp_b2)
#define WS_BN1_SS  230          // 128 (scale64, shift64)
#define WS_BN2_SS  358          // 16  (scale8, shift8)
#define WS_SYM     384          // 136*16 symmetrized bilinear weights [pair][o]
#define WS_C1F     2560         // 64*4: folded {M0,M1,M2,d} per channel
#define WS_C2T     2816         // 64*8: c2 transposed [c][c2]
#define WS_GRAM    4096         // 8 replicas * 240 Gram tile-slots
#define WS_E       8192         // NK*16
#define WS_T2      25608192     // NK*8
#define WS_XROW    38408192     // NPTS*64
#define WS_X1      44808192     // NPTS*16
// total = 46,408,192 floats = ~185.6 MB

#define GRID_NK 3125            // 3125 blocks * 256 thr * 2 iters = 1,600,000
#define NK_STRIDE 800000

// tile maps for 5x5 tile-grid (15 tiles, a<=b), packed 3 bits per tile
#define TA_PACK ((1ULL<<15)|(1ULL<<18)|(1ULL<<21)|(1ULL<<24)|(2ULL<<27)|(2ULL<<30)|(2ULL<<33)|(3ULL<<36)|(3ULL<<39)|(4ULL<<42))
#define TB_PACK ((1ULL<<3)|(2ULL<<6)|(3ULL<<9)|(4ULL<<12)|(1ULL<<15)|(2ULL<<18)|(3ULL<<21)|(4ULL<<24)|(2ULL<<27)|(3ULL<<30)|(4ULL<<33)|(3ULL<<36)|(4ULL<<39)|(4ULL<<42))

// ---------------- kernels ----------------

// per-point precompute: xrow = x@w3^T + b3 (64), X1 = x@w1[:,3:]^T + b1 (16)
__global__ __launch_bounds__(256) void k_pre(
    const float* __restrict__ x, const float* __restrict__ w3,
    const float* __restrict__ b3, const float* __restrict__ w1,
    const float* __restrict__ b1, float* __restrict__ ws)
{
    int n = blockIdx.x * 256 + threadIdx.x;
    if (n >= NPTS) return;
    float xr[64];
    const float4* xp = (const float4*)(x + (size_t)n * 64);
    #pragma unroll
    for (int i = 0; i < 16; ++i) {
        float4 v = xp[i];
        xr[4*i] = v.x; xr[4*i+1] = v.y; xr[4*i+2] = v.z; xr[4*i+3] = v.w;
    }
    float* xrow = ws + WS_XROW;
    for (int c = 0; c < 64; ++c) {
        const float* wr = w3 + c * 64;
        float a0 = b3[c], a1 = 0.f;
        #pragma unroll
        for (int q = 0; q < 64; q += 2) { a0 += wr[q] * xr[q]; a1 += wr[q+1] * xr[q+1]; }
        xrow[(size_t)n * 64 + c] = a0 + a1;
    }
    float* X1 = ws + WS_X1;
    for (int j = 0; j < 16; ++j) {
        const float* wr = w1 + j * 67 + 3;
        float a0 = b1[j], a1 = 0.f;
        #pragma unroll
        for (int q = 0; q < 64; q += 2) { a0 += wr[q] * xr[q]; a1 += wr[q+1] * xr[q+1]; }
        X1[n * 16 + j] = a0 + a1;
    }
}

// symmetrize bilinear weights: S'[pair][o], pair enumerates (i<=j)
__global__ void k_sym(const float* __restrict__ bw, float* __restrict__ ws)
{
    int t = blockIdx.x * 256 + threadIdx.x;
    if (t >= 136 * 16) return;
    int pair = t >> 4, o = t & 15;
    int i = 0, r = pair;
    while (r >= 16 - i) { r -= 16 - i; ++i; }
    int j = i + r;
    float v = bw[o * 256 + i * 16 + j];
    if (i != j) v += bw[o * 256 + j * 16 + i];
    ws[WS_SYM + pair * 16 + o] = v;
}

// BN-p stats pre-pass: pe = p_r@lp_w1^T + lp_b1 ; writes p_r and knn outputs
__global__ __launch_bounds__(256) void k_pstats(
    const float* __restrict__ p, const int* __restrict__ knn,
    const float* __restrict__ lpw1, const float* __restrict__ lpb1,
    float* __restrict__ ws, float* __restrict__ out)
{
    float ps0=0.f, ps1=0.f, ps2=0.f, pq0=0.f, pq1=0.f, pq2=0.f;
    float* o_knn = out + OUT_KNN;
    float* o_pr  = out + OUT_PR;
    int id = blockIdx.x * 256 + threadIdx.x;
    #pragma unroll 1
    for (int it = 0; it < 2; ++it, id += NK_STRIDE) {
        int n = id >> 4;
        int idx = knn[id];
        float pr0 = p[idx*3+0] - p[n*3+0];
        float pr1 = p[idx*3+1] - p[n*3+1];
        float pr2 = p[idx*3+2] - p[n*3+2];
        o_pr[id*3+0] = pr0; o_pr[id*3+1] = pr1; o_pr[id*3+2] = pr2;
        o_knn[id] = (float)idx;
        float v0 = lpb1[0] + lpw1[0]*pr0 + lpw1[1]*pr1 + lpw1[2]*pr2;
        float v1 = lpb1[1] + lpw1[3]*pr0 + lpw1[4]*pr1 + lpw1[5]*pr2;
        float v2 = lpb1[2] + lpw1[6]*pr0 + lpw1[7]*pr1 + lpw1[8]*pr2;
        ps0 += v0; ps1 += v1; ps2 += v2;
        pq0 += v0*v0; pq1 += v1*v1; pq2 += v2*v2;
    }
    #pragma unroll
    for (int off = 32; off; off >>= 1) {
        ps0 += __shfl_xor(ps0, off); ps1 += __shfl_xor(ps1, off); ps2 += __shfl_xor(ps2, off);
        pq0 += __shfl_xor(pq0, off); pq1 += __shfl_xor(pq1, off); pq2 += __shfl_xor(pq2, off);
    }
    __shared__ float sb[6];
    if (threadIdx.x < 6) sb[threadIdx.x] = 0.f;
    __syncthreads();
    if ((threadIdx.x & 63) == 0) {
        atomicAdd(&sb[0], ps0); atomicAdd(&sb[1], ps1); atomicAdd(&sb[2], ps2);
        atomicAdd(&sb[3], pq0); atomicAdd(&sb[4], pq1); atomicAdd(&sb[5], pq2);
    }
    __syncthreads();
    if (threadIdx.x < 6) atomicAdd(&ws[WS_BNP_RAW + threadIdx.x], sb[threadIdx.x]);
}

__global__ void k_fin_bnp(float* __restrict__ ws,
    const float* __restrict__ g, const float* __restrict__ b,
    const float* __restrict__ lpw2, const float* __restrict__ lpb2)
{
    int t = threadIdx.x;
    if (t < 3) {
        float mean = ws[WS_BNP_RAW + t] / (float)NK;
        float var  = ws[WS_BNP_RAW + 3 + t] / (float)NK - mean * mean;
        float sc = g[t] * rsqrtf(var + 1e-5f);
        ws[WS_BNP_SS + t] = sc;
        ws[WS_BNP_SS + 3 + t] = b[t] - mean * sc;
    }
    if (t >= 16 && t < 64) {
        int r = t - 16, j = r / 3, d = r % 3;
        ws[WS_WS2 + r] = lpw2[(j)*3+d] + lpw2[(16+j)*3+d] + lpw2[(32+j)*3+d] + lpw2[(48+j)*3+d];
    }
    if (t >= 64 && t < 80) {
        int j = t - 64;
        ws[WS_WSB + j] = lpb2[j] + lpb2[16+j] + lpb2[32+j] + lpb2[48+j];
    }
}

// fold rank-3 p-shrink path into c1; transpose c2
__global__ void k_fold(const float* __restrict__ c1w, const float* __restrict__ c2w,
                       float* __restrict__ ws)
{
    int c = threadIdx.x;
    if (c >= 64) return;
    const float* B = c1w + c * 32 + 16;
    float m0 = 0.f, m1 = 0.f, m2 = 0.f, dd = 0.f;
    #pragma unroll
    for (int j = 0; j < 16; ++j) {
        float bj = B[j];
        m0 += bj * ws[WS_WS2 + j*3 + 0];
        m1 += bj * ws[WS_WS2 + j*3 + 1];
        m2 += bj * ws[WS_WS2 + j*3 + 2];
        dd += bj * ws[WS_WSB + j];
    }
    ws[WS_C1F + c*4 + 0] = m0;
    ws[WS_C1F + c*4 + 1] = m1;
    ws[WS_C1F + c*4 + 2] = m2;
    ws[WS_C1F + c*4 + 3] = dd;
    #pragma unroll
    for (int k = 0; k < 8; ++k)
        ws[WS_C2T + c*8 + k] = c2w[k * 64 + c];
}

// main heavy pass: e (bilinear) + Gram accumulation of u = [e(16), q(3), 1]
__global__ __launch_bounds__(256) void k_stage0(
    const float* __restrict__ o_pr_in, const int* __restrict__ knn,
    const float* __restrict__ w1, const float* __restrict__ bb,
    const float* __restrict__ lpw1, const float* __restrict__ lpb1,
    const float* __restrict__ wsro, float* __restrict__ ws)
{
    __shared__ float wsym[136 * 16];           // 8.7 KB
    __shared__ __align__(16) char uni[36864];  // e1s[2][16][256] | ubuf[256][20] + gpart[15][260]
    float* e1sf  = (float*)uni;
    float* ub    = (float*)uni;
    float* gpart = (float*)(uni + 20480);
    const float* symw = wsro + WS_SYM;
    const float* X1   = wsro + WS_X1;
    float* e_out = ws + WS_E;
    int tid = threadIdx.x;
    for (int k = tid; k < 136 * 16; k += 256) wsym[k] = symw[k];

    int gid = blockIdx.x * 256 + tid;
    int id0 = gid * 2;
    float qv[2][3];

    #pragma unroll
    for (int e = 0; e < 2; ++e) {
        int id = id0 + e;
        int idx = knn[id];
        float pr0 = o_pr_in[id*3+0];
        float pr1 = o_pr_in[id*3+1];
        float pr2 = o_pr_in[id*3+2];
        // q = relu(bnp(pe))
        float v0 = lpb1[0] + lpw1[0]*pr0 + lpw1[1]*pr1 + lpw1[2]*pr2;
        float v1 = lpb1[1] + lpw1[3]*pr0 + lpw1[4]*pr1 + lpw1[5]*pr2;
        float v2 = lpb1[2] + lpw1[6]*pr0 + lpw1[7]*pr1 + lpw1[8]*pr2;
        qv[e][0] = fmaxf(v0*wsro[WS_BNP_SS+0] + wsro[WS_BNP_SS+3], 0.f);
        qv[e][1] = fmaxf(v1*wsro[WS_BNP_SS+1] + wsro[WS_BNP_SS+4], 0.f);
        qv[e][2] = fmaxf(v2*wsro[WS_BNP_SS+2] + wsro[WS_BNP_SS+5], 0.f);
        // e1 = relu(X1[idx] + Wp @ p_r)
        const float4* xg = (const float4*)(X1 + (size_t)idx * 16);
        #pragma unroll
        for (int h = 0; h < 4; ++h) {
            float4 v = xg[h];
            const float* wr = w1 + (4*h) * 67;
            e1sf[e*4096 + (4*h+0)*256 + tid] = fmaxf(v.x + wr[0]*pr0 + wr[1]*pr1 + wr[2]*pr2, 0.f);
            wr += 67;
            e1sf[e*4096 + (4*h+1)*256 + tid] = fmaxf(v.y + wr[0]*pr0 + wr[1]*pr1 + wr[2]*pr2, 0.f);
            wr += 67;
            e1sf[e*4096 + (4*h+2)*256 + tid] = fmaxf(v.z + wr[0]*pr0 + wr[1]*pr1 + wr[2]*pr2, 0.f);
            wr += 67;
            e1sf[e*4096 + (4*h+3)*256 + tid] = fmaxf(v.w + wr[0]*pr0 + wr[1]*pr1 + wr[2]*pr2, 0.f);
        }
    }
    __syncthreads();   // wsym visible

    float acc_a[16], acc_b[16];
    #pragma unroll
    for (int o = 0; o < 16; ++o) { float bo = bb[o]; acc_a[o] = bo; acc_b[o] = bo; }

    int pair = 0;
    #pragma unroll 1
    for (int i = 0; i < 16; ++i) {
        float eai = e1sf[i*256 + tid];
        float ebi = e1sf[4096 + i*256 + tid];
        #pragma unroll 1
        for (int j = i; j < 16; ++j, ++pair) {
            float eaj = e1sf[j*256 + tid];
            float ebj = e1sf[4096 + j*256 + tid];
            float ma = eai * eaj, mb = ebi * ebj;
            const float4* wp = (const float4*)(wsym + pair * 16);
            float4 w0v = wp[0], w1v = wp[1], w2v = wp[2], w3v = wp[3];
            acc_a[0]  += w0v.x*ma; acc_a[1]  += w0v.y*ma; acc_a[2]  += w0v.z*ma; acc_a[3]  += w0v.w*ma;
            acc_a[4]  += w1v.x*ma; acc_a[5]  += w1v.y*ma; acc_a[6]  += w1v.z*ma; acc_a[7]  += w1v.w*ma;
            acc_a[8]  += w2v.x*ma; acc_a[9]  += w2v.y*ma; acc_a[10] += w2v.z*ma; acc_a[11] += w2v.w*ma;
            acc_a[12] += w3v.x*ma; acc_a[13] += w3v.y*ma; acc_a[14] += w3v.z*ma; acc_a[15] += w3v.w*ma;
            acc_b[0]  += w0v.x*mb; acc_b[1]  += w0v.y*mb; acc_b[2]  += w0v.z*mb; acc_b[3]  += w0v.w*mb;
            acc_b[4]  += w1v.x*mb; acc_b[5]  += w1v.y*mb; acc_b[6]  += w1v.z*mb; acc_b[7]  += w1v.w*mb;
            acc_b[8]  += w2v.x*mb; acc_b[9]  += w2v.y*mb; acc_b[10] += w2v.z*mb; acc_b[11] += w2v.w*mb;
            acc_b[12] += w3v.x*mb; acc_b[13] += w3v.y*mb; acc_b[14] += w3v.z*mb; acc_b[15] += w3v.w*mb;
        }
    }
    float4* eo = (float4*)(e_out + (size_t)id0 * 16);
    eo[0] = make_float4(acc_a[0],  acc_a[1],  acc_a[2],  acc_a[3]);
    eo[1] = make_float4(acc_a[4],  acc_a[5],  acc_a[6],  acc_a[7]);
    eo[2] = make_float4(acc_a[8],  acc_a[9],  acc_a[10], acc_a[11]);
    eo[3] = make_float4(acc_a[12], acc_a[13], acc_a[14], acc_a[15]);
    eo[4] = make_float4(acc_b[0],  acc_b[1],  acc_b[2],  acc_b[3]);
    eo[5] = make_float4(acc_b[4],  acc_b[5],  acc_b[6],  acc_b[7]);
    eo[6] = make_float4(acc_b[8],  acc_b[9],  acc_b[10], acc_b[11]);
    eo[7] = make_float4(acc_b[12], acc_b[13], acc_b[14], acc_b[15]);

    // ---- Gram phase: two rounds of 256 elements through ubuf ----
    int l = tid & 15, g = tid >> 4;
    int tt = (l + g * 4) % 15;                 // tile id (bijective per group)
    int a4 = (int)((TA_PACK >> (3*tt)) & 7) * 4;
    int b4 = (int)((TB_PACK >> (3*tt)) & 7) * 4;
    float gacc[16];
    #pragma unroll
    for (int k = 0; k < 16; ++k) gacc[k] = 0.f;

    #pragma unroll 1
    for (int rnd = 0; rnd < 2; ++rnd) {
        __syncthreads();                       // prev phase reads done
        if ((tid >> 7) == rnd) {
            int s0 = (tid & 127) * 2;
            #pragma unroll
            for (int e = 0; e < 2; ++e) {
                int s = s0 + e;
                const float* ac = e ? acc_b : acc_a;
                float u[20];
                #pragma unroll
                for (int k = 0; k < 16; ++k) u[k] = ac[k];
                u[16] = qv[e][0]; u[17] = qv[e][1]; u[18] = qv[e][2]; u[19] = 1.f;
                int rot = (s % 5) * 4;
                #pragma unroll
                for (int k = 0; k < 5; ++k) {
                    int phys = (4*k + rot) % 20;
                    *(float4*)(ub + s*20 + phys) = make_float4(u[4*k], u[4*k+1], u[4*k+2], u[4*k+3]);
                }
            }
        }
        __syncthreads();
        if (l < 15) {
            #pragma unroll 1
            for (int it2 = 0; it2 < 16; ++it2) {
                int s = g * 16 + it2;
                int rot = (s % 5) * 4;
                const float4 ua  = *(const float4*)(ub + s*20 + ((a4 + rot) % 20));
                const float4 ub4 = *(const float4*)(ub + s*20 + ((b4 + rot) % 20));
                gacc[0]  += ua.x*ub4.x; gacc[1]  += ua.x*ub4.y; gacc[2]  += ua.x*ub4.z; gacc[3]  += ua.x*ub4.w;
                gacc[4]  += ua.y*ub4.x; gacc[5]  += ua.y*ub4.y; gacc[6]  += ua.y*ub4.z; gacc[7]  += ua.y*ub4.w;
                gacc[8]  += ua.z*ub4.x; gacc[9]  += ua.z*ub4.y; gacc[10] += ua.z*ub4.z; gacc[11] += ua.z*ub4.w;
                gacc[12] += ua.w*ub4.x; gacc[13] += ua.w*ub4.y; gacc[14] += ua.w*ub4.z; gacc[15] += ua.w*ub4.w;
            }
        }
    }
    __syncthreads();
    if (l < 15) {
        #pragma unroll
        for (int k = 0; k < 16; ++k) gpart[tt*260 + k*16 + g] = gacc[k];
    }
    __syncthreads();
    if (tid < 240) {
        int t2 = tid >> 4, k2 = tid & 15;
        int base = t2 * 260 + k2 * 16;
        float s = 0.f;
        #pragma unroll
        for (int g2 = 0; g2 < 16; ++g2) s += gpart[base + g2];
        atomicAdd(&ws[WS_GRAM + (blockIdx.x & 7) * 240 + tid], s);
    }
}

// finalize BN1 from Gram: mean_c = A'G[:,19]/N, ssq_c = A'^T G A'
__global__ __launch_bounds__(256) void k_fin_bn1(
    const float* __restrict__ c1w, const float* __restrict__ g,
    const float* __restrict__ b, float* __restrict__ ws)
{
    __shared__ float Gs[240];
    __shared__ float Gfull[400];
    __shared__ float Ach[64][21];
    int tid = threadIdx.x;
    if (tid < 240) {
        float s = 0.f;
        #pragma unroll
        for (int r = 0; r < 8; ++r) s += ws[WS_GRAM + r*240 + tid];
        Gs[tid] = s;
    }
    if (tid < 64) {
        #pragma unroll
        for (int k = 0; k < 16; ++k) Ach[tid][k] = c1w[tid*32 + k];
        Ach[tid][16] = ws[WS_C1F + tid*4 + 0];
        Ach[tid][17] = ws[WS_C1F + tid*4 + 1];
        Ach[tid][18] = ws[WS_C1F + tid*4 + 2];
        Ach[tid][19] = ws[WS_C1F + tid*4 + 3];
    }
    __syncthreads();
    for (int idx = tid; idx < 400; idx += 256) {
        int i = idx / 20, j = idx % 20;
        int a = i >> 2, ra = i & 3, bt = j >> 2, cb = j & 3;
        float v;
        if (a <= bt) {
            int t = a*5 - (a*(a-1))/2 + (bt - a);
            v = Gs[t*16 + ra*4 + cb];
        } else {
            int t = bt*5 - (bt*(bt-1))/2 + (a - bt);
            v = Gs[t*16 + cb*4 + ra];
        }
        Gfull[idx] = v;
    }
    __syncthreads();
    if (tid < 64) {
        float s1 = 0.f, ssq = 0.f;
        #pragma unroll 1
        for (int i = 0; i < 20; ++i) {
            float Ai = Ach[tid][i];
            s1 += Ai * Gfull[i*20 + 19];
            float inner = 0.f;
            #pragma unroll
            for (int j = 0; j < 20; ++j) inner += Ach[tid][j] * Gfull[i*20 + j];
            ssq += Ai * inner;
        }
        float mean = s1 / (float)NK;
        float var  = ssq / (float)NK - mean * mean;
        float sc = g[tid] * rsqrtf(var + 1e-5f);
        ws[WS_BN1_SS + tid] = sc;
        ws[WS_BN1_SS + 64 + tid] = b[tid] - mean * sc;
    }
}

// load e[16] + q[3] for one element
__device__ __forceinline__ void build_eq(
    const float* __restrict__ e_in, const float* __restrict__ o_pr,
    const float* __restrict__ lpw1, const float* __restrict__ lpb1,
    const float* __restrict__ wsro, int id, float* e, float* q)
{
    const float4* ep = (const float4*)(e_in + (size_t)id * 16);
    #pragma unroll
    for (int i = 0; i < 4; ++i) {
        float4 v = ep[i];
        e[4*i] = v.x; e[4*i+1] = v.y; e[4*i+2] = v.z; e[4*i+3] = v.w;
    }
    float pr0 = o_pr[id*3+0], pr1 = o_pr[id*3+1], pr2 = o_pr[id*3+2];
    float v0 = lpb1[0] + lpw1[0]*pr0 + lpw1[1]*pr1 + lpw1[2]*pr2;
    float v1 = lpb1[1] + lpw1[3]*pr0 + lpw1[4]*pr1 + lpw1[5]*pr2;
    float v2 = lpb1[2] + lpw1[6]*pr0 + lpw1[7]*pr1 + lpw1[8]*pr2;
    q[0] = fmaxf(v0*wsro[WS_BNP_SS+0] + wsro[WS_BNP_SS+3], 0.f);
    q[1] = fmaxf(v1*wsro[WS_BNP_SS+1] + wsro[WS_BNP_SS+4], 0.f);
    q[2] = fmaxf(v2*wsro[WS_BNP_SS+2] + wsro[WS_BNP_SS+5], 0.f);
}

// stage2: t2 = c2 @ relu(bn1(h1)); 4 elements per thread to amortize
// wave-uniform weight loads (each 128B of c1w feeds ~160 FMA)
#define S2_GRID 1563            // ceil(NK / 1024)
__global__ __launch_bounds__(256) void k_stage2(
    const float* __restrict__ wsro, const float* __restrict__ out_ro,
    const float* __restrict__ lpw1, const float* __restrict__ lpb1,
    const float* __restrict__ c1w, float* __restrict__ ws)
{
    float tsum[8] = {0,0,0,0,0,0,0,0}, tssq[8] = {0,0,0,0,0,0,0,0};
    const float* e_in = wsro + WS_E;
    const float* o_pr = out_ro + OUT_PR;
    float* t2 = ws + WS_T2;
    int base = blockIdx.x * 1024 + threadIdx.x;
    int ids[4];
    bool valid[4];
    float e[4][16], q[4][3];
    #pragma unroll
    for (int v = 0; v < 4; ++v) {
        ids[v] = base + v * 256;
        valid[v] = ids[v] < NK;
        if (valid[v]) build_eq(e_in, o_pr, lpw1, lpb1, wsro, ids[v], e[v], q[v]);
        else {
            #pragma unroll
            for (int k = 0; k < 16; ++k) e[v][k] = 0.f;
            q[v][0] = q[v][1] = q[v][2] = 0.f;
        }
    }
    float t2a[4][8];
    #pragma unroll
    for (int v = 0; v < 4; ++v)
        #pragma unroll
        for (int c2 = 0; c2 < 8; ++c2) t2a[v][c2] = 0.f;

    #pragma unroll 1
    for (int c = 0; c < 64; c += 2) {
        const float* wa = c1w + c * 32;
        const float* wb = wa + 32;
        const float4 fa = *(const float4*)(wsro + WS_C1F + c*4);
        const float4 fb = *(const float4*)(wsro + WS_C1F + c*4 + 4);
        float sc0 = wsro[WS_BN1_SS + c],     sh0 = wsro[WS_BN1_SS + 64 + c];
        float sc1 = wsro[WS_BN1_SS + c + 1], sh1 = wsro[WS_BN1_SS + 65 + c];
        const float4 ca0 = *(const float4*)(wsro + WS_C2T + c*8);
        const float4 ca1 = *(const float4*)(wsro + WS_C2T + c*8 + 4);
        const float4 cb0 = *(const float4*)(wsro + WS_C2T + c*8 + 8);
        const float4 cb1 = *(const float4*)(wsro + WS_C2T + c*8 + 12);
        #pragma unroll
        for (int v = 0; v < 4; ++v) {
            float h0 = fa.w + fa.x*q[v][0] + fa.y*q[v][1] + fa.z*q[v][2];
            float h1 = fb.w + fb.x*q[v][0] + fb.y*q[v][1] + fb.z*q[v][2];
            #pragma unroll
            for (int k = 0; k < 16; ++k) {
                h0 += wa[k]*e[v][k]; h1 += wb[k]*e[v][k];
            }
            h0 = fmaxf(h0 * sc0 + sh0, 0.f);
            h1 = fmaxf(h1 * sc1 + sh1, 0.f);
            t2a[v][0] += h0*ca0.x + h1*cb0.x; t2a[v][1] += h0*ca0.y + h1*cb0.y;
            t2a[v][2] += h0*ca0.z + h1*cb0.z; t2a[v][3] += h0*ca0.w + h1*cb0.w;
            t2a[v][4] += h0*ca1.x + h1*cb1.x; t2a[v][5] += h0*ca1.y + h1*cb1.y;
            t2a[v][6] += h0*ca1.z + h1*cb1.z; t2a[v][7] += h0*ca1.w + h1*cb1.w;
        }
    }
    #pragma unroll
    for (int v = 0; v < 4; ++v) {
        if (!valid[v]) continue;
        float4* t2p = (float4*)(t2 + (size_t)ids[v] * 8);
        t2p[0] = make_float4(t2a[v][0], t2a[v][1], t2a[v][2], t2a[v][3]);
        t2p[1] = make_float4(t2a[v][4], t2a[v][5], t2a[v][6], t2a[v][7]);
        #pragma unroll
        for (int c2 = 0; c2 < 8; ++c2) { tsum[c2] += t2a[v][c2]; tssq[c2] += t2a[v][c2] * t2a[v][c2]; }
    }
    __shared__ float sacc[16];
    if (threadIdx.x < 16) sacc[threadIdx.x] = 0.f;
    __syncthreads();
    #pragma unroll
    for (int c2 = 0; c2 < 8; ++c2) {
        float s = tsum[c2], s2 = tssq[c2];
        #pragma unroll
        for (int off = 32; off; off >>= 1) { s += __shfl_xor(s, off); s2 += __shfl_xor(s2, off); }
        if ((threadIdx.x & 63) == 0) { atomicAdd(&sacc[c2], s); atomicAdd(&sacc[8 + c2], s2); }
    }
    __syncthreads();
    if (threadIdx.x < 16) atomicAdd(&ws[WS_BN2_RAW + threadIdx.x], sacc[threadIdx.x]);
}

__global__ void k_fin_bn2(float* __restrict__ ws, const float* __restrict__ g, const float* __restrict__ b)
{
    int c = threadIdx.x;
    if (c < 8) {
        float mean = ws[WS_BN2_RAW + c] / (float)NK;
        float var  = ws[WS_BN2_RAW + 8 + c] / (float)NK - mean * mean;
        float sc = g[c] * rsqrtf(var + 1e-5f);
        ws[WS_BN2_SS + c] = sc;
        ws[WS_BN2_SS + 8 + c] = b[c] - mean * sc;
    }
}

// 2 points per 256-thread block (sub = t>>7)
__global__ __launch_bounds__(256) void k_final(
    const int* __restrict__ knn, const float* __restrict__ wsro,
    const float* __restrict__ c3w, const float* __restrict__ c3b,
    const float* __restrict__ lpw1, const float* __restrict__ lpb1,
    const float* __restrict__ lpw2, const float* __restrict__ lpb2,
    float* __restrict__ out)
{
    int t = threadIdx.x;
    int sub = t >> 7, tl = t & 127;
    int n = blockIdx.x * 2 + sub;
    __shared__ float h2s[2][16][8], ssm[2][16][8], wls[2][16][8], pes[2][16][3], prs[2][48], red[2][128];
    __shared__ int idxs[2][16];
    const float* t2   = wsro + WS_T2;
    const float* o_pr = out + OUT_PR;
    const float* xrow = wsro + WS_XROW;
    if (tl < 16) idxs[sub][tl] = knn[n * 16 + tl];
    if (tl < 48) prs[sub][tl] = o_pr[(size_t)n * 48 + tl];
    {
        int k = tl >> 3, c2 = tl & 7;
        float v = t2[(size_t)n * 128 + tl];
        h2s[sub][k][c2] = fmaxf(v * wsro[WS_BN2_SS + c2] + wsro[WS_BN2_SS + 8 + c2], 0.f);
    }
    __syncthreads();
    if (tl < 48) {
        int k = tl / 3, d = tl % 3;
        float pe = lpb1[d] + lpw1[d*3+0]*prs[sub][k*3+0] + lpw1[d*3+1]*prs[sub][k*3+1] + lpw1[d*3+2]*prs[sub][k*3+2];
        pes[sub][k][d] = fmaxf(pe * wsro[WS_BNP_SS + d] + wsro[WS_BNP_SS + 3 + d], 0.f);
    }
    {
        int k = tl >> 3, cc = tl & 7;
        float s = c3b[cc];
        #pragma unroll
        for (int q = 0; q < 8; ++q) s += h2s[sub][k][q] * c3w[cc * 8 + q];
        ssm[sub][k][cc] = s;
    }
    __syncthreads();
    if (tl < 8) {
        float m = -1e30f;
        for (int k = 0; k < 16; ++k) m = fmaxf(m, ssm[sub][k][tl]);
        float sum = 0.f;
        for (int k = 0; k < 16; ++k) { float ev = __expf(ssm[sub][k][tl] - m); wls[sub][k][tl] = ev; sum += ev; }
        float inv = 1.f / sum;
        for (int k = 0; k < 16; ++k) wls[sub][k][tl] *= inv;
    }
    __syncthreads();
    int c = tl & 63, kh = tl >> 6;
    float w20 = lpw2[c*3], w21 = lpw2[c*3+1], w22 = lpw2[c*3+2], bc = lpb2[c];
    float acc = 0.f;
    float* out_xk = out + OUT_XK + (size_t)n * 1024;
    #pragma unroll
    for (int i = 0; i < 8; ++i) {
        int k = kh * 8 + i;
        float xv = xrow[(size_t)idxs[sub][k] * 64 + c];
        float pemb = bc + w20 * pes[sub][k][0] + w21 * pes[sub][k][1] + w22 * pes[sub][k][2];
        float val = (xv + pemb) * wls[sub][k][c & 7];
        out_xk[k * 64 + c] = val;
        acc += val;
    }
    red[sub][tl] = acc;
    __syncthreads();
    if (tl < 64) out[(size_t)n * 64 + tl] = red[sub][tl] + red[sub][tl + 64];
}

// ---------------- launch ----------------
extern "C" void kernel_launch(void* const* d_in, const int* in_sizes, int n_in,
                              void* d_out, int out_size, void* d_ws, size_t ws_size,
                              hipStream_t stream)
{
    (void)in_sizes; (void)n_in; (void)out_size; (void)ws_size;
    const float* p    = (const float*)d_in[0];
    const float* x    = (const float*)d_in[1];
    const int*   knn  = (const int*)  d_in[2];
    const float* w1   = (const float*)d_in[3];
    const float* b1   = (const float*)d_in[4];
    const float* bw   = (const float*)d_in[5];
    const float* bb   = (const float*)d_in[6];
    const float* lpw1 = (const float*)d_in[7];
    const float* lpb1 = (const float*)d_in[8];
    const float* bnpg = (const float*)d_in[9];
    const float* bnpb = (const float*)d_in[10];
    const float* lpw2 = (const float*)d_in[11];
    const float* lpb2 = (const float*)d_in[12];
    const float* c1w  = (const float*)d_in[13];
    const float* bn1g = (const float*)d_in[14];
    const float* bn1b = (const float*)d_in[15];
    const float* c2w  = (const float*)d_in[16];
    const float* bn2g = (const float*)d_in[17];
    const float* bn2b = (const float*)d_in[18];
    const float* c3w  = (const float*)d_in[19];
    const float* c3b  = (const float*)d_in[20];
    const float* w3   = (const float*)d_in[21];
    const float* b3   = (const float*)d_in[22];
    float* out = (float*)d_out;
    float* ws  = (float*)d_ws;

    (void)hipMemsetAsync(ws, 0, 6016 * sizeof(float), stream);
    k_pre   <<<(NPTS + 255) / 256, 256, 0, stream>>>(x, w3, b3, w1, b1, ws);
    k_sym   <<<9, 256, 0, stream>>>(bw, ws);
    k_pstats<<<GRID_NK, 256, 0, stream>>>(p, knn, lpw1, lpb1, ws, out);
    k_fin_bnp<<<1, 128, 0, stream>>>(ws, bnpg, bnpb, lpw2, lpb2);
    k_fold  <<<1, 64, 0, stream>>>(c1w, c2w, ws);
    k_stage0<<<GRID_NK, 256, 0, stream>>>(out + OUT_PR, knn, w1, bb, lpw1, lpb1, ws, ws);
    k_fin_bn1<<<1, 256, 0, stream>>>(c1w, bn1g, bn1b, ws);
    k_stage2<<<S2_GRID, 256, 0, stream>>>(ws, out, lpw1, lpb1, c1w, ws);
    k_fin_bn2<<<1, 64, 0, stream>>>(ws, bn2g, bn2b);
    k_final <<<NPTS / 2, 256, 0, stream>>>(knn, ws, c3w, c3b, lpw1, lpb1, lpw2, lpb2, out);
}

// Round 11
// 587.342 us; speedup vs baseline: 1.0462x; 1.0462x over previous
//
#include <hip/hip_runtime.h>
#include <math.h>

// ---------------- problem constants ----------------
#define NPTS 100000
#define KNB  16
#define NK   1600000            // NPTS*KNB

// output layout (float offsets)
#define OUT_XK   6400000        // after x_out [N,64]
#define OUT_KNN  108800000      // after xk [N,16,64]
#define OUT_PR   110400000      // after knn [N,16]

// workspace layout (float offsets)
#define WS_BNP_RAW 0            // 6   (sum3, ssq3)
#define WS_BN2_RAW 134          // 16  (sum8, ssq8)
#define WS_BNP_SS  160          // 6   (scale3, shift3)
#define WS_WS2     166          // 48  (16x3 shrunk lp_w2)
#define WS_WSB     214          // 16  (shrunk lp_b2)
#define WS_BN1_SS  230          // 128 (scale64, shift64)
#define WS_BN2_SS  358          // 16  (scale8, shift8)
#define WS_SYM     384          // 136*16 symmetrized bilinear weights [pair][o]
#define WS_C1F     2560         // 64*4: folded {M0,M1,M2,d} per channel
#define WS_C2T     2816         // 64*8: c2 transposed [c][c2]
#define WS_GRAM    4096         // 8 replicas * 240 Gram tile-slots
#define WS_E       8192         // NK*16
#define WS_T2      25608192     // NK*8
#define WS_XROW    38408192     // NPTS*64
#define WS_X1      44808192     // NPTS*16
// total = 46,408,192 floats = ~185.6 MB

#define GRID_NK 3125            // 3125 blocks * 256 thr * 2 iters = 1,600,000
#define NK_STRIDE 800000

// tile maps for 5x5 tile-grid (15 tiles, a<=b), packed 3 bits per tile
#define TA_PACK ((1ULL<<15)|(1ULL<<18)|(1ULL<<21)|(1ULL<<24)|(2ULL<<27)|(2ULL<<30)|(2ULL<<33)|(3ULL<<36)|(3ULL<<39)|(4ULL<<42))
#define TB_PACK ((1ULL<<3)|(2ULL<<6)|(3ULL<<9)|(4ULL<<12)|(1ULL<<15)|(2ULL<<18)|(3ULL<<21)|(4ULL<<24)|(2ULL<<27)|(3ULL<<30)|(4ULL<<33)|(3ULL<<36)|(4ULL<<39)|(4ULL<<42))

// ---------------- kernels ----------------

// per-point precompute: xrow = x@w3^T + b3 (64), X1 = x@w1[:,3:]^T + b1 (16)
__global__ __launch_bounds__(256) void k_pre(
    const float* __restrict__ x, const float* __restrict__ w3,
    const float* __restrict__ b3, const float* __restrict__ w1,
    const float* __restrict__ b1, float* __restrict__ ws)
{
    int n = blockIdx.x * 256 + threadIdx.x;
    if (n >= NPTS) return;
    float xr[64];
    const float4* xp = (const float4*)(x + (size_t)n * 64);
    #pragma unroll
    for (int i = 0; i < 16; ++i) {
        float4 v = xp[i];
        xr[4*i] = v.x; xr[4*i+1] = v.y; xr[4*i+2] = v.z; xr[4*i+3] = v.w;
    }
    float* xrow = ws + WS_XROW;
    for (int c = 0; c < 64; ++c) {
        const float* wr = w3 + c * 64;
        float a0 = b3[c], a1 = 0.f;
        #pragma unroll
        for (int q = 0; q < 64; q += 2) { a0 += wr[q] * xr[q]; a1 += wr[q+1] * xr[q+1]; }
        xrow[(size_t)n * 64 + c] = a0 + a1;
    }
    float* X1 = ws + WS_X1;
    for (int j = 0; j < 16; ++j) {
        const float* wr = w1 + j * 67 + 3;
        float a0 = b1[j], a1 = 0.f;
        #pragma unroll
        for (int q = 0; q < 64; q += 2) { a0 += wr[q] * xr[q]; a1 += wr[q+1] * xr[q+1]; }
        X1[n * 16 + j] = a0 + a1;
    }
}

// symmetrize bilinear weights: S'[pair][o], pair enumerates (i<=j)
__global__ void k_sym(const float* __restrict__ bw, float* __restrict__ ws)
{
    int t = blockIdx.x * 256 + threadIdx.x;
    if (t >= 136 * 16) return;
    int pair = t >> 4, o = t & 15;
    int i = 0, r = pair;
    while (r >= 16 - i) { r -= 16 - i; ++i; }
    int j = i + r;
    float v = bw[o * 256 + i * 16 + j];
    if (i != j) v += bw[o * 256 + j * 16 + i];
    ws[WS_SYM + pair * 16 + o] = v;
}

// BN-p stats pre-pass: pe = p_r@lp_w1^T + lp_b1 ; writes p_r and knn outputs
__global__ __launch_bounds__(256) void k_pstats(
    const float* __restrict__ p, const int* __restrict__ knn,
    const float* __restrict__ lpw1, const float* __restrict__ lpb1,
    float* __restrict__ ws, float* __restrict__ out)
{
    float ps0=0.f, ps1=0.f, ps2=0.f, pq0=0.f, pq1=0.f, pq2=0.f;
    float* o_knn = out + OUT_KNN;
    float* o_pr  = out + OUT_PR;
    int id = blockIdx.x * 256 + threadIdx.x;
    #pragma unroll 1
    for (int it = 0; it < 2; ++it, id += NK_STRIDE) {
        int n = id >> 4;
        int idx = knn[id];
        float pr0 = p[idx*3+0] - p[n*3+0];
        float pr1 = p[idx*3+1] - p[n*3+1];
        float pr2 = p[idx*3+2] - p[n*3+2];
        o_pr[id*3+0] = pr0; o_pr[id*3+1] = pr1; o_pr[id*3+2] = pr2;
        o_knn[id] = (float)idx;
        float v0 = lpb1[0] + lpw1[0]*pr0 + lpw1[1]*pr1 + lpw1[2]*pr2;
        float v1 = lpb1[1] + lpw1[3]*pr0 + lpw1[4]*pr1 + lpw1[5]*pr2;
        float v2 = lpb1[2] + lpw1[6]*pr0 + lpw1[7]*pr1 + lpw1[8]*pr2;
        ps0 += v0; ps1 += v1; ps2 += v2;
        pq0 += v0*v0; pq1 += v1*v1; pq2 += v2*v2;
    }
    #pragma unroll
    for (int off = 32; off; off >>= 1) {
        ps0 += __shfl_xor(ps0, off); ps1 += __shfl_xor(ps1, off); ps2 += __shfl_xor(ps2, off);
        pq0 += __shfl_xor(pq0, off); pq1 += __shfl_xor(pq1, off); pq2 += __shfl_xor(pq2, off);
    }
    __shared__ float sb[6];
    if (threadIdx.x < 6) sb[threadIdx.x] = 0.f;
    __syncthreads();
    if ((threadIdx.x & 63) == 0) {
        atomicAdd(&sb[0], ps0); atomicAdd(&sb[1], ps1); atomicAdd(&sb[2], ps2);
        atomicAdd(&sb[3], pq0); atomicAdd(&sb[4], pq1); atomicAdd(&sb[5], pq2);
    }
    __syncthreads();
    if (threadIdx.x < 6) atomicAdd(&ws[WS_BNP_RAW + threadIdx.x], sb[threadIdx.x]);
}

__global__ void k_fin_bnp(float* __restrict__ ws,
    const float* __restrict__ g, const float* __restrict__ b,
    const float* __restrict__ lpw2, const float* __restrict__ lpb2)
{
    int t = threadIdx.x;
    if (t < 3) {
        float mean = ws[WS_BNP_RAW + t] / (float)NK;
        float var  = ws[WS_BNP_RAW + 3 + t] / (float)NK - mean * mean;
        float sc = g[t] * rsqrtf(var + 1e-5f);
        ws[WS_BNP_SS + t] = sc;
        ws[WS_BNP_SS + 3 + t] = b[t] - mean * sc;
    }
    if (t >= 16 && t < 64) {
        int r = t - 16, j = r / 3, d = r % 3;
        ws[WS_WS2 + r] = lpw2[(j)*3+d] + lpw2[(16+j)*3+d] + lpw2[(32+j)*3+d] + lpw2[(48+j)*3+d];
    }
    if (t >= 64 && t < 80) {
        int j = t - 64;
        ws[WS_WSB + j] = lpb2[j] + lpb2[16+j] + lpb2[32+j] + lpb2[48+j];
    }
}

// fold rank-3 p-shrink path into c1; transpose c2
__global__ void k_fold(const float* __restrict__ c1w, const float* __restrict__ c2w,
                       float* __restrict__ ws)
{
    int c = threadIdx.x;
    if (c >= 64) return;
    const float* B = c1w + c * 32 + 16;
    float m0 = 0.f, m1 = 0.f, m2 = 0.f, dd = 0.f;
    #pragma unroll
    for (int j = 0; j < 16; ++j) {
        float bj = B[j];
        m0 += bj * ws[WS_WS2 + j*3 + 0];
        m1 += bj * ws[WS_WS2 + j*3 + 1];
        m2 += bj * ws[WS_WS2 + j*3 + 2];
        dd += bj * ws[WS_WSB + j];
    }
    ws[WS_C1F + c*4 + 0] = m0;
    ws[WS_C1F + c*4 + 1] = m1;
    ws[WS_C1F + c*4 + 2] = m2;
    ws[WS_C1F + c*4 + 3] = dd;
    #pragma unroll
    for (int k = 0; k < 8; ++k)
        ws[WS_C2T + c*8 + k] = c2w[k * 64 + c];
}

// main heavy pass: e (bilinear) + Gram accumulation of u = [e(16), q(3), 1]
// bilinear weights read via wave-uniform GLOBAL pointer (scalar cache, s_load)
// to keep the shared per-CU LDS pipe free for the per-thread e1 reads.
__global__ __launch_bounds__(256) void k_stage0(
    const float* __restrict__ o_pr_in, const int* __restrict__ knn,
    const float* __restrict__ w1, const float* __restrict__ bb,
    const float* __restrict__ lpw1, const float* __restrict__ lpb1,
    const float* __restrict__ wsro, float* __restrict__ ws)
{
    __shared__ __align__(16) char uni[36864];  // e1s[2][16][256] | ubuf[256][20] + gpart[15][260]
    float* e1sf  = (float*)uni;
    float* ub    = (float*)uni;
    float* gpart = (float*)(uni + 20480);
    const float* symw = wsro + WS_SYM;
    const float* X1   = wsro + WS_X1;
    float* e_out = ws + WS_E;
    int tid = threadIdx.x;

    int gid = blockIdx.x * 256 + tid;
    int id0 = gid * 2;
    float qv[2][3];

    #pragma unroll
    for (int e = 0; e < 2; ++e) {
        int id = id0 + e;
        int idx = knn[id];
        float pr0 = o_pr_in[id*3+0];
        float pr1 = o_pr_in[id*3+1];
        float pr2 = o_pr_in[id*3+2];
        // q = relu(bnp(pe))
        float v0 = lpb1[0] + lpw1[0]*pr0 + lpw1[1]*pr1 + lpw1[2]*pr2;
        float v1 = lpb1[1] + lpw1[3]*pr0 + lpw1[4]*pr1 + lpw1[5]*pr2;
        float v2 = lpb1[2] + lpw1[6]*pr0 + lpw1[7]*pr1 + lpw1[8]*pr2;
        qv[e][0] = fmaxf(v0*wsro[WS_BNP_SS+0] + wsro[WS_BNP_SS+3], 0.f);
        qv[e][1] = fmaxf(v1*wsro[WS_BNP_SS+1] + wsro[WS_BNP_SS+4], 0.f);
        qv[e][2] = fmaxf(v2*wsro[WS_BNP_SS+2] + wsro[WS_BNP_SS+5], 0.f);
        // e1 = relu(X1[idx] + Wp @ p_r)
        const float4* xg = (const float4*)(X1 + (size_t)idx * 16);
        #pragma unroll
        for (int h = 0; h < 4; ++h) {
            float4 v = xg[h];
            const float* wr = w1 + (4*h) * 67;
            e1sf[e*4096 + (4*h+0)*256 + tid] = fmaxf(v.x + wr[0]*pr0 + wr[1]*pr1 + wr[2]*pr2, 0.f);
            wr += 67;
            e1sf[e*4096 + (4*h+1)*256 + tid] = fmaxf(v.y + wr[0]*pr0 + wr[1]*pr1 + wr[2]*pr2, 0.f);
            wr += 67;
            e1sf[e*4096 + (4*h+2)*256 + tid] = fmaxf(v.z + wr[0]*pr0 + wr[1]*pr1 + wr[2]*pr2, 0.f);
            wr += 67;
            e1sf[e*4096 + (4*h+3)*256 + tid] = fmaxf(v.w + wr[0]*pr0 + wr[1]*pr1 + wr[2]*pr2, 0.f);
        }
    }
    __syncthreads();

    float acc_a[16], acc_b[16];
    #pragma unroll
    for (int o = 0; o < 16; ++o) { float bo = bb[o]; acc_a[o] = bo; acc_b[o] = bo; }

    int pair = 0;
    #pragma unroll 1
    for (int i = 0; i < 16; ++i) {
        float eai = e1sf[i*256 + tid];
        float ebi = e1sf[4096 + i*256 + tid];
        #pragma unroll 2
        for (int j = i; j < 16; ++j, ++pair) {
            float eaj = e1sf[j*256 + tid];
            float ebj = e1sf[4096 + j*256 + tid];
            float ma = eai * eaj, mb = ebi * ebj;
            const float4* wp = (const float4*)(symw + pair * 16);  // uniform -> s_load
            float4 w0v = wp[0], w1v = wp[1], w2v = wp[2], w3v = wp[3];
            acc_a[0]  += w0v.x*ma; acc_a[1]  += w0v.y*ma; acc_a[2]  += w0v.z*ma; acc_a[3]  += w0v.w*ma;
            acc_a[4]  += w1v.x*ma; acc_a[5]  += w1v.y*ma; acc_a[6]  += w1v.z*ma; acc_a[7]  += w1v.w*ma;
            acc_a[8]  += w2v.x*ma; acc_a[9]  += w2v.y*ma; acc_a[10] += w2v.z*ma; acc_a[11] += w2v.w*ma;
            acc_a[12] += w3v.x*ma; acc_a[13] += w3v.y*ma; acc_a[14] += w3v.z*ma; acc_a[15] += w3v.w*ma;
            acc_b[0]  += w0v.x*mb; acc_b[1]  += w0v.y*mb; acc_b[2]  += w0v.z*mb; acc_b[3]  += w0v.w*mb;
            acc_b[4]  += w1v.x*mb; acc_b[5]  += w1v.y*mb; acc_b[6]  += w1v.z*mb; acc_b[7]  += w1v.w*mb;
            acc_b[8]  += w2v.x*mb; acc_b[9]  += w2v.y*mb; acc_b[10] += w2v.z*mb; acc_b[11] += w2v.w*mb;
            acc_b[12] += w3v.x*mb; acc_b[13] += w3v.y*mb; acc_b[14] += w3v.z*mb; acc_b[15] += w3v.w*mb;
        }
    }
    float4* eo = (float4*)(e_out + (size_t)id0 * 16);
    eo[0] = make_float4(acc_a[0],  acc_a[1],  acc_a[2],  acc_a[3]);
    eo[1] = make_float4(acc_a[4],  acc_a[5],  acc_a[6],  acc_a[7]);
    eo[2] = make_float4(acc_a[8],  acc_a[9],  acc_a[10], acc_a[11]);
    eo[3] = make_float4(acc_a[12], acc_a[13], acc_a[14], acc_a[15]);
    eo[4] = make_float4(acc_b[0],  acc_b[1],  acc_b[2],  acc_b[3]);
    eo[5] = make_float4(acc_b[4],  acc_b[5],  acc_b[6],  acc_b[7]);
    eo[6] = make_float4(acc_b[8],  acc_b[9],  acc_b[10], acc_b[11]);
    eo[7] = make_float4(acc_b[12], acc_b[13], acc_b[14], acc_b[15]);

    // ---- Gram phase: two rounds of 256 elements through ubuf ----
    int l = tid & 15, g = tid >> 4;
    int tt = (l + g * 4) % 15;                 // tile id (bijective per group)
    int a4 = (int)((TA_PACK >> (3*tt)) & 7) * 4;
    int b4 = (int)((TB_PACK >> (3*tt)) & 7) * 4;
    float gacc[16];
    #pragma unroll
    for (int k = 0; k < 16; ++k) gacc[k] = 0.f;

    #pragma unroll 1
    for (int rnd = 0; rnd < 2; ++rnd) {
        __syncthreads();                       // prev phase reads done
        if ((tid >> 7) == rnd) {
            int s0 = (tid & 127) * 2;
            #pragma unroll
            for (int e = 0; e < 2; ++e) {
                int s = s0 + e;
                const float* ac = e ? acc_b : acc_a;
                float u[20];
                #pragma unroll
                for (int k = 0; k < 16; ++k) u[k] = ac[k];
                u[16] = qv[e][0]; u[17] = qv[e][1]; u[18] = qv[e][2]; u[19] = 1.f;
                int rot = (s % 5) * 4;
                #pragma unroll
                for (int k = 0; k < 5; ++k) {
                    int phys = (4*k + rot) % 20;
                    *(float4*)(ub + s*20 + phys) = make_float4(u[4*k], u[4*k+1], u[4*k+2], u[4*k+3]);
                }
            }
        }
        __syncthreads();
        if (l < 15) {
            #pragma unroll 1
            for (int it2 = 0; it2 < 16; ++it2) {
                int s = g * 16 + it2;
                int rot = (s % 5) * 4;
                const float4 ua  = *(const float4*)(ub + s*20 + ((a4 + rot) % 20));
                const float4 ub4 = *(const float4*)(ub + s*20 + ((b4 + rot) % 20));
                gacc[0]  += ua.x*ub4.x; gacc[1]  += ua.x*ub4.y; gacc[2]  += ua.x*ub4.z; gacc[3]  += ua.x*ub4.w;
                gacc[4]  += ua.y*ub4.x; gacc[5]  += ua.y*ub4.y; gacc[6]  += ua.y*ub4.z; gacc[7]  += ua.y*ub4.w;
                gacc[8]  += ua.z*ub4.x; gacc[9]  += ua.z*ub4.y; gacc[10] += ua.z*ub4.z; gacc[11] += ua.z*ub4.w;
                gacc[12] += ua.w*ub4.x; gacc[13] += ua.w*ub4.y; gacc[14] += ua.w*ub4.z; gacc[15] += ua.w*ub4.w;
            }
        }
    }
    __syncthreads();
    if (l < 15) {
        #pragma unroll
        for (int k = 0; k < 16; ++k) gpart[tt*260 + k*16 + g] = gacc[k];
    }
    __syncthreads();
    if (tid < 240) {
        int t2 = tid >> 4, k2 = tid & 15;
        int base = t2 * 260 + k2 * 16;
        float s = 0.f;
        #pragma unroll
        for (int g2 = 0; g2 < 16; ++g2) s += gpart[base + g2];
        atomicAdd(&ws[WS_GRAM + (blockIdx.x & 7) * 240 + tid], s);
    }
}

// finalize BN1 from Gram: mean_c = A'G[:,19]/N, ssq_c = A'^T G A'
__global__ __launch_bounds__(256) void k_fin_bn1(
    const float* __restrict__ c1w, const float* __restrict__ g,
    const float* __restrict__ b, float* __restrict__ ws)
{
    __shared__ float Gs[240];
    __shared__ float Gfull[400];
    __shared__ float Ach[64][21];
    int tid = threadIdx.x;
    if (tid < 240) {
        float s = 0.f;
        #pragma unroll
        for (int r = 0; r < 8; ++r) s += ws[WS_GRAM + r*240 + tid];
        Gs[tid] = s;
    }
    if (tid < 64) {
        #pragma unroll
        for (int k = 0; k < 16; ++k) Ach[tid][k] = c1w[tid*32 + k];
        Ach[tid][16] = ws[WS_C1F + tid*4 + 0];
        Ach[tid][17] = ws[WS_C1F + tid*4 + 1];
        Ach[tid][18] = ws[WS_C1F + tid*4 + 2];
        Ach[tid][19] = ws[WS_C1F + tid*4 + 3];
    }
    __syncthreads();
    for (int idx = tid; idx < 400; idx += 256) {
        int i = idx / 20, j = idx % 20;
        int a = i >> 2, ra = i & 3, bt = j >> 2, cb = j & 3;
        float v;
        if (a <= bt) {
            int t = a*5 - (a*(a-1))/2 + (bt - a);
            v = Gs[t*16 + ra*4 + cb];
        } else {
            int t = bt*5 - (bt*(bt-1))/2 + (a - bt);
            v = Gs[t*16 + cb*4 + ra];
        }
        Gfull[idx] = v;
    }
    __syncthreads();
    if (tid < 64) {
        float s1 = 0.f, ssq = 0.f;
        #pragma unroll 1
        for (int i = 0; i < 20; ++i) {
            float Ai = Ach[tid][i];
            s1 += Ai * Gfull[i*20 + 19];
            float inner = 0.f;
            #pragma unroll
            for (int j = 0; j < 20; ++j) inner += Ach[tid][j] * Gfull[i*20 + j];
            ssq += Ai * inner;
        }
        float mean = s1 / (float)NK;
        float var  = ssq / (float)NK - mean * mean;
        float sc = g[tid] * rsqrtf(var + 1e-5f);
        ws[WS_BN1_SS + tid] = sc;
        ws[WS_BN1_SS + 64 + tid] = b[tid] - mean * sc;
    }
}

// load e[16] + q[3] for one element
__device__ __forceinline__ void build_eq(
    const float* __restrict__ e_in, const float* __restrict__ o_pr,
    const float* __restrict__ lpw1, const float* __restrict__ lpb1,
    const float* __restrict__ wsro, int id, float* e, float* q)
{
    const float4* ep = (const float4*)(e_in + (size_t)id * 16);
    #pragma unroll
    for (int i = 0; i < 4; ++i) {
        float4 v = ep[i];
        e[4*i] = v.x; e[4*i+1] = v.y; e[4*i+2] = v.z; e[4*i+3] = v.w;
    }
    float pr0 = o_pr[id*3+0], pr1 = o_pr[id*3+1], pr2 = o_pr[id*3+2];
    float v0 = lpb1[0] + lpw1[0]*pr0 + lpw1[1]*pr1 + lpw1[2]*pr2;
    float v1 = lpb1[1] + lpw1[3]*pr0 + lpw1[4]*pr1 + lpw1[5]*pr2;
    float v2 = lpb1[2] + lpw1[6]*pr0 + lpw1[7]*pr1 + lpw1[8]*pr2;
    q[0] = fmaxf(v0*wsro[WS_BNP_SS+0] + wsro[WS_BNP_SS+3], 0.f);
    q[1] = fmaxf(v1*wsro[WS_BNP_SS+1] + wsro[WS_BNP_SS+4], 0.f);
    q[2] = fmaxf(v2*wsro[WS_BNP_SS+2] + wsro[WS_BNP_SS+5], 0.f);
}

// stage2 (r9 form): t2 = c2 @ relu(bn1(h1)), h1 via folded form; BN2 stats
__global__ __launch_bounds__(256) void k_stage2(
    const float* __restrict__ wsro, const float* __restrict__ out_ro,
    const float* __restrict__ lpw1, const float* __restrict__ lpb1,
    const float* __restrict__ c1w, float* __restrict__ ws)
{
    float tsum[8] = {0,0,0,0,0,0,0,0}, tssq[8] = {0,0,0,0,0,0,0,0};
    const float* e_in = wsro + WS_E;
    const float* o_pr = out_ro + OUT_PR;
    float* t2 = ws + WS_T2;
    int id = blockIdx.x * 256 + threadIdx.x;
    #pragma unroll 1
    for (int it = 0; it < 2; ++it, id += NK_STRIDE) {
        float e[16], q[3];
        build_eq(e_in, o_pr, lpw1, lpb1, wsro, id, e, q);
        float t2a[8] = {0,0,0,0,0,0,0,0};
        #pragma unroll 1
        for (int c = 0; c < 64; c += 2) {
            const float* wa = c1w + c * 32;
            const float* wb = wa + 32;
            const float4 fa = *(const float4*)(wsro + WS_C1F + c*4);
            const float4 fb = *(const float4*)(wsro + WS_C1F + c*4 + 4);
            float h0 = fa.w + fa.x*q[0] + fa.y*q[1] + fa.z*q[2];
            float h1 = fb.w + fb.x*q[0] + fb.y*q[1] + fb.z*q[2];
            #pragma unroll
            for (int k = 0; k < 16; ++k) {
                h0 += wa[k]*e[k]; h1 += wb[k]*e[k];
            }
            h0 = fmaxf(h0 * wsro[WS_BN1_SS + c]     + wsro[WS_BN1_SS + 64 + c], 0.f);
            h1 = fmaxf(h1 * wsro[WS_BN1_SS + c + 1] + wsro[WS_BN1_SS + 65 + c], 0.f);
            const float4 ca0 = *(const float4*)(wsro + WS_C2T + c*8);
            const float4 ca1 = *(const float4*)(wsro + WS_C2T + c*8 + 4);
            const float4 cb0 = *(const float4*)(wsro + WS_C2T + c*8 + 8);
            const float4 cb1 = *(const float4*)(wsro + WS_C2T + c*8 + 12);
            t2a[0] += h0*ca0.x + h1*cb0.x; t2a[1] += h0*ca0.y + h1*cb0.y;
            t2a[2] += h0*ca0.z + h1*cb0.z; t2a[3] += h0*ca0.w + h1*cb0.w;
            t2a[4] += h0*ca1.x + h1*cb1.x; t2a[5] += h0*ca1.y + h1*cb1.y;
            t2a[6] += h0*ca1.z + h1*cb1.z; t2a[7] += h0*ca1.w + h1*cb1.w;
        }
        float4* t2p = (float4*)(t2 + (size_t)id * 8);
        t2p[0] = make_float4(t2a[0], t2a[1], t2a[2], t2a[3]);
        t2p[1] = make_float4(t2a[4], t2a[5], t2a[6], t2a[7]);
        #pragma unroll
        for (int c2 = 0; c2 < 8; ++c2) { tsum[c2] += t2a[c2]; tssq[c2] += t2a[c2] * t2a[c2]; }
    }
    __shared__ float sacc[16];
    if (threadIdx.x < 16) sacc[threadIdx.x] = 0.f;
    __syncthreads();
    #pragma unroll
    for (int c2 = 0; c2 < 8; ++c2) {
        float s = tsum[c2], s2 = tssq[c2];
        #pragma unroll
        for (int off = 32; off; off >>= 1) { s += __shfl_xor(s, off); s2 += __shfl_xor(s2, off); }
        if ((threadIdx.x & 63) == 0) { atomicAdd(&sacc[c2], s); atomicAdd(&sacc[8 + c2], s2); }
    }
    __syncthreads();
    if (threadIdx.x < 16) atomicAdd(&ws[WS_BN2_RAW + threadIdx.x], sacc[threadIdx.x]);
}

__global__ void k_fin_bn2(float* __restrict__ ws, const float* __restrict__ g, const float* __restrict__ b)
{
    int c = threadIdx.x;
    if (c < 8) {
        float mean = ws[WS_BN2_RAW + c] / (float)NK;
        float var  = ws[WS_BN2_RAW + 8 + c] / (float)NK - mean * mean;
        float sc = g[c] * rsqrtf(var + 1e-5f);
        ws[WS_BN2_SS + c] = sc;
        ws[WS_BN2_SS + 8 + c] = b[c] - mean * sc;
    }
}

// 2 points per 256-thread block (sub = t>>7)
__global__ __launch_bounds__(256) void k_final(
    const int* __restrict__ knn, const float* __restrict__ wsro,
    const float* __restrict__ c3w, const float* __restrict__ c3b,
    const float* __restrict__ lpw1, const float* __restrict__ lpb1,
    const float* __restrict__ lpw2, const float* __restrict__ lpb2,
    float* __restrict__ out)
{
    int t = threadIdx.x;
    int sub = t >> 7, tl = t & 127;
    int n = blockIdx.x * 2 + sub;
    __shared__ float h2s[2][16][8], ssm[2][16][8], wls[2][16][8], pes[2][16][3], prs[2][48], red[2][128];
    __shared__ int idxs[2][16];
    const float* t2   = wsro + WS_T2;
    const float* o_pr = out + OUT_PR;
    const float* xrow = wsro + WS_XROW;
    if (tl < 16) idxs[sub][tl] = knn[n * 16 + tl];
    if (tl < 48) prs[sub][tl] = o_pr[(size_t)n * 48 + tl];
    {
        int k = tl >> 3, c2 = tl & 7;
        float v = t2[(size_t)n * 128 + tl];
        h2s[sub][k][c2] = fmaxf(v * wsro[WS_BN2_SS + c2] + wsro[WS_BN2_SS + 8 + c2], 0.f);
    }
    __syncthreads();
    if (tl < 48) {
        int k = tl / 3, d = tl % 3;
        float pe = lpb1[d] + lpw1[d*3+0]*prs[sub][k*3+0] + lpw1[d*3+1]*prs[sub][k*3+1] + lpw1[d*3+2]*prs[sub][k*3+2];
        pes[sub][k][d] = fmaxf(pe * wsro[WS_BNP_SS + d] + wsro[WS_BNP_SS + 3 + d], 0.f);
    }
    {
        int k = tl >> 3, cc = tl & 7;
        float s = c3b[cc];
        #pragma unroll
        for (int q = 0; q < 8; ++q) s += h2s[sub][k][q] * c3w[cc * 8 + q];
        ssm[sub][k][cc] = s;
    }
    __syncthreads();
    if (tl < 8) {
        float m = -1e30f;
        for (int k = 0; k < 16; ++k) m = fmaxf(m, ssm[sub][k][tl]);
        float sum = 0.f;
        for (int k = 0; k < 16; ++k) { float ev = __expf(ssm[sub][k][tl] - m); wls[sub][k][tl] = ev; sum += ev; }
        float inv = 1.f / sum;
        for (int k = 0; k < 16; ++k) wls[sub][k][tl] *= inv;
    }
    __syncthreads();
    int c = tl & 63, kh = tl >> 6;
    float w20 = lpw2[c*3], w21 = lpw2[c*3+1], w22 = lpw2[c*3+2], bc = lpb2[c];
    float acc = 0.f;
    float* out_xk = out + OUT_XK + (size_t)n * 1024;
    #pragma unroll
    for (int i = 0; i < 8; ++i) {
        int k = kh * 8 + i;
        float xv = xrow[(size_t)idxs[sub][k] * 64 + c];
        float pemb = bc + w20 * pes[sub][k][0] + w21 * pes[sub][k][1] + w22 * pes[sub][k][2];
        float val = (xv + pemb) * wls[sub][k][c & 7];
        out_xk[k * 64 + c] = val;
        acc += val;
    }
    red[sub][tl] = acc;
    __syncthreads();
    if (tl < 64) out[(size_t)n * 64 + tl] = red[sub][tl] + red[sub][tl + 64];
}

// ---------------- launch ----------------
extern "C" void kernel_launch(void* const* d_in, const int* in_sizes, int n_in,
                              void* d_out, int out_size, void* d_ws, size_t ws_size,
                              hipStream_t stream)
{
    (void)in_sizes; (void)n_in; (void)out_size; (void)ws_size;
    const float* p    = (const float*)d_in[0];
    const float* x    = (const float*)d_in[1];
    const int*   knn  = (const int*)  d_in[2];
    const float* w1   = (const float*)d_in[3];
    const float* b1   = (const float*)d_in[4];
    const float* bw   = (const float*)d_in[5];
    const float* bb   = (const float*)d_in[6];
    const float* lpw1 = (const float*)d_in[7];
    const float* lpb1 = (const float*)d_in[8];
    const float* bnpg = (const float*)d_in[9];
    const float* bnpb = (const float*)d_in[10];
    const float* lpw2 = (const float*)d_in[11];
    const float* lpb2 = (const float*)d_in[12];
    const float* c1w  = (const float*)d_in[13];
    const float* bn1g = (const float*)d_in[14];
    const float* bn1b = (const float*)d_in[15];
    const float* c2w  = (const float*)d_in[16];
    const float* bn2g = (const float*)d_in[17];
    const float* bn2b = (const float*)d_in[18];
    const float* c3w  = (const float*)d_in[19];
    const float* c3b  = (const float*)d_in[20];
    const float* w3   = (const float*)d_in[21];
    const float* b3   = (const float*)d_in[22];
    float* out = (float*)d_out;
    float* ws  = (float*)d_ws;

    (void)hipMemsetAsync(ws, 0, 6016 * sizeof(float), stream);
    k_pre   <<<(NPTS + 255) / 256, 256, 0, stream>>>(x, w3, b3, w1, b1, ws);
    k_sym   <<<9, 256, 0, stream>>>(bw, ws);
    k_pstats<<<GRID_NK, 256, 0, stream>>>(p, knn, lpw1, lpb1, ws, out);
    k_fin_bnp<<<1, 128, 0, stream>>>(ws, bnpg, bnpb, lpw2, lpb2);
    k_fold  <<<1, 64, 0, stream>>>(c1w, c2w, ws);
    k_stage0<<<GRID_NK, 256, 0, stream>>>(out + OUT_PR, knn, w1, bb, lpw1, lpb1, ws, ws);
    k_fin_bn1<<<1, 256, 0, stream>>>(c1w, bn1g, bn1b, ws);
    k_stage2<<<GRID_NK, 256, 0, stream>>>(ws, out, lpw1, lpb1, c1w, ws);
    k_fin_bn2<<<1, 64, 0, stream>>>(ws, bn2g, bn2b);
    k_final <<<NPTS / 2, 256, 0, stream>>>(knn, ws, c3w, c3b, lpw1, lpb1, lpw2, lpb2, out);
}

// Round 12
// 583.676 us; speedup vs baseline: 1.0527x; 1.0063x over previous
//
#include <hip/hip_runtime.h>
#include <math.h>

// ---------------- problem constants ----------------
#define NPTS 100000
#define KNB  16
#define NK   1600000            // NPTS*KNB

// output layout (float offsets)
#define OUT_XK   6400000        // after x_out [N,64]
#define OUT_KNN  108800000      // after xk [N,16,64]
#define OUT_PR   110400000      // after knn [N,16]

// workspace layout (float offsets)
#define WS_BNP_RAW 0            // 6   (sum3, ssq3)
#define WS_BN2_RAW 134          // 16  (sum8, ssq8)
#define WS_BNP_SS  160          // 6   (scale3, shift3)
#define WS_WS2     166          // 48  (16x3 shrunk lp_w2)
#define WS_WSB     214          // 16  (shrunk lp_b2)
#define WS_BN1_SS  230          // 128 (scale64, shift64)
#define WS_BN2_SS  358          // 16  (scale8, shift8)
#define WS_SYM     384          // 136*16 symmetrized bilinear weights [pair][o]
#define WS_C1F     2560         // 64*4: folded {M0,M1,M2,d} per channel
#define WS_C2T     2816         // 64*8: c2 transposed [c][c2]
#define WS_GRAM    4096         // 8 replicas * 240 Gram tile-slots
#define WS_E       8192         // NK*16
#define WS_T2      25608192     // NK*8
#define WS_XROW    38408192     // NPTS*64
#define WS_X1      44808192     // NPTS*16
// total = 46,408,192 floats = ~185.6 MB

#define GRID_NK 3125            // 3125 blocks * 256 thr * 2 iters = 1,600,000
#define NK_STRIDE 800000

// tile maps for 5x5 tile-grid (15 tiles, a<=b), packed 3 bits per tile
#define TA_PACK ((1ULL<<15)|(1ULL<<18)|(1ULL<<21)|(1ULL<<24)|(2ULL<<27)|(2ULL<<30)|(2ULL<<33)|(3ULL<<36)|(3ULL<<39)|(4ULL<<42))
#define TB_PACK ((1ULL<<3)|(2ULL<<6)|(3ULL<<9)|(4ULL<<12)|(1ULL<<15)|(2ULL<<18)|(3ULL<<21)|(4ULL<<24)|(2ULL<<27)|(3ULL<<30)|(4ULL<<33)|(3ULL<<36)|(4ULL<<39)|(4ULL<<42))

// ---------------- kernels ----------------

// per-point precompute: xrow = x@w3^T + b3 (64), X1 = x@w1[:,3:]^T + b1 (16)
__global__ __launch_bounds__(256) void k_pre(
    const float* __restrict__ x, const float* __restrict__ w3,
    const float* __restrict__ b3, const float* __restrict__ w1,
    const float* __restrict__ b1, float* __restrict__ ws)
{
    int n = blockIdx.x * 256 + threadIdx.x;
    if (n >= NPTS) return;
    float xr[64];
    const float4* xp = (const float4*)(x + (size_t)n * 64);
    #pragma unroll
    for (int i = 0; i < 16; ++i) {
        float4 v = xp[i];
        xr[4*i] = v.x; xr[4*i+1] = v.y; xr[4*i+2] = v.z; xr[4*i+3] = v.w;
    }
    float* xrow = ws + WS_XROW;
    for (int c = 0; c < 64; ++c) {
        const float* wr = w3 + c * 64;
        float a0 = b3[c], a1 = 0.f;
        #pragma unroll
        for (int q = 0; q < 64; q += 2) { a0 += wr[q] * xr[q]; a1 += wr[q+1] * xr[q+1]; }
        xrow[(size_t)n * 64 + c] = a0 + a1;
    }
    float* X1 = ws + WS_X1;
    for (int j = 0; j < 16; ++j) {
        const float* wr = w1 + j * 67 + 3;
        float a0 = b1[j], a1 = 0.f;
        #pragma unroll
        for (int q = 0; q < 64; q += 2) { a0 += wr[q] * xr[q]; a1 += wr[q+1] * xr[q+1]; }
        X1[n * 16 + j] = a0 + a1;
    }
}

// symmetrize bilinear weights: S'[pair][o], pair enumerates (i<=j)
__global__ void k_sym(const float* __restrict__ bw, float* __restrict__ ws)
{
    int t = blockIdx.x * 256 + threadIdx.x;
    if (t >= 136 * 16) return;
    int pair = t >> 4, o = t & 15;
    int i = 0, r = pair;
    while (r >= 16 - i) { r -= 16 - i; ++i; }
    int j = i + r;
    float v = bw[o * 256 + i * 16 + j];
    if (i != j) v += bw[o * 256 + j * 16 + i];
    ws[WS_SYM + pair * 16 + o] = v;
}

// BN-p stats pre-pass: pe = p_r@lp_w1^T + lp_b1 ; writes p_r and knn outputs
__global__ __launch_bounds__(256) void k_pstats(
    const float* __restrict__ p, const int* __restrict__ knn,
    const float* __restrict__ lpw1, const float* __restrict__ lpb1,
    float* __restrict__ ws, float* __restrict__ out)
{
    float ps0=0.f, ps1=0.f, ps2=0.f, pq0=0.f, pq1=0.f, pq2=0.f;
    float* o_knn = out + OUT_KNN;
    float* o_pr  = out + OUT_PR;
    int id = blockIdx.x * 256 + threadIdx.x;
    #pragma unroll 1
    for (int it = 0; it < 2; ++it, id += NK_STRIDE) {
        int n = id >> 4;
        int idx = knn[id];
        float pr0 = p[idx*3+0] - p[n*3+0];
        float pr1 = p[idx*3+1] - p[n*3+1];
        float pr2 = p[idx*3+2] - p[n*3+2];
        o_pr[id*3+0] = pr0; o_pr[id*3+1] = pr1; o_pr[id*3+2] = pr2;
        o_knn[id] = (float)idx;
        float v0 = lpb1[0] + lpw1[0]*pr0 + lpw1[1]*pr1 + lpw1[2]*pr2;
        float v1 = lpb1[1] + lpw1[3]*pr0 + lpw1[4]*pr1 + lpw1[5]*pr2;
        float v2 = lpb1[2] + lpw1[6]*pr0 + lpw1[7]*pr1 + lpw1[8]*pr2;
        ps0 += v0; ps1 += v1; ps2 += v2;
        pq0 += v0*v0; pq1 += v1*v1; pq2 += v2*v2;
    }
    #pragma unroll
    for (int off = 32; off; off >>= 1) {
        ps0 += __shfl_xor(ps0, off); ps1 += __shfl_xor(ps1, off); ps2 += __shfl_xor(ps2, off);
        pq0 += __shfl_xor(pq0, off); pq1 += __shfl_xor(pq1, off); pq2 += __shfl_xor(pq2, off);
    }
    __shared__ float sb[6];
    if (threadIdx.x < 6) sb[threadIdx.x] = 0.f;
    __syncthreads();
    if ((threadIdx.x & 63) == 0) {
        atomicAdd(&sb[0], ps0); atomicAdd(&sb[1], ps1); atomicAdd(&sb[2], ps2);
        atomicAdd(&sb[3], pq0); atomicAdd(&sb[4], pq1); atomicAdd(&sb[5], pq2);
    }
    __syncthreads();
    if (threadIdx.x < 6) atomicAdd(&ws[WS_BNP_RAW + threadIdx.x], sb[threadIdx.x]);
}

__global__ void k_fin_bnp(float* __restrict__ ws,
    const float* __restrict__ g, const float* __restrict__ b,
    const float* __restrict__ lpw2, const float* __restrict__ lpb2)
{
    int t = threadIdx.x;
    if (t < 3) {
        float mean = ws[WS_BNP_RAW + t] / (float)NK;
        float var  = ws[WS_BNP_RAW + 3 + t] / (float)NK - mean * mean;
        float sc = g[t] * rsqrtf(var + 1e-5f);
        ws[WS_BNP_SS + t] = sc;
        ws[WS_BNP_SS + 3 + t] = b[t] - mean * sc;
    }
    if (t >= 16 && t < 64) {
        int r = t - 16, j = r / 3, d = r % 3;
        ws[WS_WS2 + r] = lpw2[(j)*3+d] + lpw2[(16+j)*3+d] + lpw2[(32+j)*3+d] + lpw2[(48+j)*3+d];
    }
    if (t >= 64 && t < 80) {
        int j = t - 64;
        ws[WS_WSB + j] = lpb2[j] + lpb2[16+j] + lpb2[32+j] + lpb2[48+j];
    }
}

// fold rank-3 p-shrink path into c1; transpose c2
__global__ void k_fold(const float* __restrict__ c1w, const float* __restrict__ c2w,
                       float* __restrict__ ws)
{
    int c = threadIdx.x;
    if (c >= 64) return;
    const float* B = c1w + c * 32 + 16;
    float m0 = 0.f, m1 = 0.f, m2 = 0.f, dd = 0.f;
    #pragma unroll
    for (int j = 0; j < 16; ++j) {
        float bj = B[j];
        m0 += bj * ws[WS_WS2 + j*3 + 0];
        m1 += bj * ws[WS_WS2 + j*3 + 1];
        m2 += bj * ws[WS_WS2 + j*3 + 2];
        dd += bj * ws[WS_WSB + j];
    }
    ws[WS_C1F + c*4 + 0] = m0;
    ws[WS_C1F + c*4 + 1] = m1;
    ws[WS_C1F + c*4 + 2] = m2;
    ws[WS_C1F + c*4 + 3] = dd;
    #pragma unroll
    for (int k = 0; k < 8; ++k)
        ws[WS_C2T + c*8 + k] = c2w[k * 64 + c];
}

// main heavy pass: e (bilinear) + Gram accumulation of u = [e(16), q(3), 1]
__global__ __launch_bounds__(256) void k_stage0(
    const float* __restrict__ o_pr_in, const int* __restrict__ knn,
    const float* __restrict__ w1, const float* __restrict__ bb,
    const float* __restrict__ lpw1, const float* __restrict__ lpb1,
    const float* __restrict__ wsro, float* __restrict__ ws)
{
    __shared__ __align__(16) char uni[36864];  // e1s[2][16][256] | ubuf[256][20] + gpart[15][260]
    float* e1sf  = (float*)uni;
    float* ub    = (float*)uni;
    float* gpart = (float*)(uni + 20480);
    const float* symw = wsro + WS_SYM;
    const float* X1   = wsro + WS_X1;
    float* e_out = ws + WS_E;
    int tid = threadIdx.x;

    int gid = blockIdx.x * 256 + tid;
    int id0 = gid * 2;
    float qv[2][3];

    #pragma unroll
    for (int e = 0; e < 2; ++e) {
        int id = id0 + e;
        int idx = knn[id];
        float pr0 = o_pr_in[id*3+0];
        float pr1 = o_pr_in[id*3+1];
        float pr2 = o_pr_in[id*3+2];
        float v0 = lpb1[0] + lpw1[0]*pr0 + lpw1[1]*pr1 + lpw1[2]*pr2;
        float v1 = lpb1[1] + lpw1[3]*pr0 + lpw1[4]*pr1 + lpw1[5]*pr2;
        float v2 = lpb1[2] + lpw1[6]*pr0 + lpw1[7]*pr1 + lpw1[8]*pr2;
        qv[e][0] = fmaxf(v0*wsro[WS_BNP_SS+0] + wsro[WS_BNP_SS+3], 0.f);
        qv[e][1] = fmaxf(v1*wsro[WS_BNP_SS+1] + wsro[WS_BNP_SS+4], 0.f);
        qv[e][2] = fmaxf(v2*wsro[WS_BNP_SS+2] + wsro[WS_BNP_SS+5], 0.f);
        const float4* xg = (const float4*)(X1 + (size_t)idx * 16);
        #pragma unroll
        for (int h = 0; h < 4; ++h) {
            float4 v = xg[h];
            const float* wr = w1 + (4*h) * 67;
            e1sf[e*4096 + (4*h+0)*256 + tid] = fmaxf(v.x + wr[0]*pr0 + wr[1]*pr1 + wr[2]*pr2, 0.f);
            wr += 67;
            e1sf[e*4096 + (4*h+1)*256 + tid] = fmaxf(v.y + wr[0]*pr0 + wr[1]*pr1 + wr[2]*pr2, 0.f);
            wr += 67;
            e1sf[e*4096 + (4*h+2)*256 + tid] = fmaxf(v.z + wr[0]*pr0 + wr[1]*pr1 + wr[2]*pr2, 0.f);
            wr += 67;
            e1sf[e*4096 + (4*h+3)*256 + tid] = fmaxf(v.w + wr[0]*pr0 + wr[1]*pr1 + wr[2]*pr2, 0.f);
        }
    }
    __syncthreads();

    float acc_a[16], acc_b[16];
    #pragma unroll
    for (int o = 0; o < 16; ++o) { float bo = bb[o]; acc_a[o] = bo; acc_b[o] = bo; }

    int pair = 0;
    #pragma unroll 1
    for (int i = 0; i < 16; ++i) {
        float eai = e1sf[i*256 + tid];
        float ebi = e1sf[4096 + i*256 + tid];
        #pragma unroll 2
        for (int j = i; j < 16; ++j, ++pair) {
            float eaj = e1sf[j*256 + tid];
            float ebj = e1sf[4096 + j*256 + tid];
            float ma = eai * eaj, mb = ebi * ebj;
            const float4* wp = (const float4*)(symw + pair * 16);  // uniform -> s_load
            float4 w0v = wp[0], w1v = wp[1], w2v = wp[2], w3v = wp[3];
            acc_a[0]  += w0v.x*ma; acc_a[1]  += w0v.y*ma; acc_a[2]  += w0v.z*ma; acc_a[3]  += w0v.w*ma;
            acc_a[4]  += w1v.x*ma; acc_a[5]  += w1v.y*ma; acc_a[6]  += w1v.z*ma; acc_a[7]  += w1v.w*ma;
            acc_a[8]  += w2v.x*ma; acc_a[9]  += w2v.y*ma; acc_a[10] += w2v.z*ma; acc_a[11] += w2v.w*ma;
            acc_a[12] += w3v.x*ma; acc_a[13] += w3v.y*ma; acc_a[14] += w3v.z*ma; acc_a[15] += w3v.w*ma;
            acc_b[0]  += w0v.x*mb; acc_b[1]  += w0v.y*mb; acc_b[2]  += w0v.z*mb; acc_b[3]  += w0v.w*mb;
            acc_b[4]  += w1v.x*mb; acc_b[5]  += w1v.y*mb; acc_b[6]  += w1v.z*mb; acc_b[7]  += w1v.w*mb;
            acc_b[8]  += w2v.x*mb; acc_b[9]  += w2v.y*mb; acc_b[10] += w2v.z*mb; acc_b[11] += w2v.w*mb;
            acc_b[12] += w3v.x*mb; acc_b[13] += w3v.y*mb; acc_b[14] += w3v.z*mb; acc_b[15] += w3v.w*mb;
        }
    }
    float4* eo = (float4*)(e_out + (size_t)id0 * 16);
    eo[0] = make_float4(acc_a[0],  acc_a[1],  acc_a[2],  acc_a[3]);
    eo[1] = make_float4(acc_a[4],  acc_a[5],  acc_a[6],  acc_a[7]);
    eo[2] = make_float4(acc_a[8],  acc_a[9],  acc_a[10], acc_a[11]);
    eo[3] = make_float4(acc_a[12], acc_a[13], acc_a[14], acc_a[15]);
    eo[4] = make_float4(acc_b[0],  acc_b[1],  acc_b[2],  acc_b[3]);
    eo[5] = make_float4(acc_b[4],  acc_b[5],  acc_b[6],  acc_b[7]);
    eo[6] = make_float4(acc_b[8],  acc_b[9],  acc_b[10], acc_b[11]);
    eo[7] = make_float4(acc_b[12], acc_b[13], acc_b[14], acc_b[15]);

    // ---- Gram phase ----
    int l = tid & 15, g = tid >> 4;
    int tt = (l + g * 4) % 15;
    int a4 = (int)((TA_PACK >> (3*tt)) & 7) * 4;
    int b4 = (int)((TB_PACK >> (3*tt)) & 7) * 4;
    float gacc[16];
    #pragma unroll
    for (int k = 0; k < 16; ++k) gacc[k] = 0.f;

    #pragma unroll 1
    for (int rnd = 0; rnd < 2; ++rnd) {
        __syncthreads();
        if ((tid >> 7) == rnd) {
            int s0 = (tid & 127) * 2;
            #pragma unroll
            for (int e = 0; e < 2; ++e) {
                int s = s0 + e;
                const float* ac = e ? acc_b : acc_a;
                float u[20];
                #pragma unroll
                for (int k = 0; k < 16; ++k) u[k] = ac[k];
                u[16] = qv[e][0]; u[17] = qv[e][1]; u[18] = qv[e][2]; u[19] = 1.f;
                int rot = (s % 5) * 4;
                #pragma unroll
                for (int k = 0; k < 5; ++k) {
                    int phys = (4*k + rot) % 20;
                    *(float4*)(ub + s*20 + phys) = make_float4(u[4*k], u[4*k+1], u[4*k+2], u[4*k+3]);
                }
            }
        }
        __syncthreads();
        if (l < 15) {
            #pragma unroll 1
            for (int it2 = 0; it2 < 16; ++it2) {
                int s = g * 16 + it2;
                int rot = (s % 5) * 4;
                const float4 ua  = *(const float4*)(ub + s*20 + ((a4 + rot) % 20));
                const float4 ub4 = *(const float4*)(ub + s*20 + ((b4 + rot) % 20));
                gacc[0]  += ua.x*ub4.x; gacc[1]  += ua.x*ub4.y; gacc[2]  += ua.x*ub4.z; gacc[3]  += ua.x*ub4.w;
                gacc[4]  += ua.y*ub4.x; gacc[5]  += ua.y*ub4.y; gacc[6]  += ua.y*ub4.z; gacc[7]  += ua.y*ub4.w;
                gacc[8]  += ua.z*ub4.x; gacc[9]  += ua.z*ub4.y; gacc[10] += ua.z*ub4.z; gacc[11] += ua.z*ub4.w;
                gacc[12] += ua.w*ub4.x; gacc[13] += ua.w*ub4.y; gacc[14] += ua.w*ub4.z; gacc[15] += ua.w*ub4.w;
            }
        }
    }
    __syncthreads();
    if (l < 15) {
        #pragma unroll
        for (int k = 0; k < 16; ++k) gpart[tt*260 + k*16 + g] = gacc[k];
    }
    __syncthreads();
    if (tid < 240) {
        int t2 = tid >> 4, k2 = tid & 15;
        int base = t2 * 260 + k2 * 16;
        float s = 0.f;
        #pragma unroll
        for (int g2 = 0; g2 < 16; ++g2) s += gpart[base + g2];
        atomicAdd(&ws[WS_GRAM + (blockIdx.x & 7) * 240 + tid], s);
    }
}

// finalize BN1 from Gram
__global__ __launch_bounds__(256) void k_fin_bn1(
    const float* __restrict__ c1w, const float* __restrict__ g,
    const float* __restrict__ b, float* __restrict__ ws)
{
    __shared__ float Gs[240];
    __shared__ float Gfull[400];
    __shared__ float Ach[64][21];
    int tid = threadIdx.x;
    if (tid < 240) {
        float s = 0.f;
        #pragma unroll
        for (int r = 0; r < 8; ++r) s += ws[WS_GRAM + r*240 + tid];
        Gs[tid] = s;
    }
    if (tid < 64) {
        #pragma unroll
        for (int k = 0; k < 16; ++k) Ach[tid][k] = c1w[tid*32 + k];
        Ach[tid][16] = ws[WS_C1F + tid*4 + 0];
        Ach[tid][17] = ws[WS_C1F + tid*4 + 1];
        Ach[tid][18] = ws[WS_C1F + tid*4 + 2];
        Ach[tid][19] = ws[WS_C1F + tid*4 + 3];
    }
    __syncthreads();
    for (int idx = tid; idx < 400; idx += 256) {
        int i = idx / 20, j = idx % 20;
        int a = i >> 2, ra = i & 3, bt = j >> 2, cb = j & 3;
        float v;
        if (a <= bt) {
            int t = a*5 - (a*(a-1))/2 + (bt - a);
            v = Gs[t*16 + ra*4 + cb];
        } else {
            int t = bt*5 - (bt*(bt-1))/2 + (a - bt);
            v = Gs[t*16 + cb*4 + ra];
        }
        Gfull[idx] = v;
    }
    __syncthreads();
    if (tid < 64) {
        float s1 = 0.f, ssq = 0.f;
        #pragma unroll 1
        for (int i = 0; i < 20; ++i) {
            float Ai = Ach[tid][i];
            s1 += Ai * Gfull[i*20 + 19];
            float inner = 0.f;
            #pragma unroll
            for (int j = 0; j < 20; ++j) inner += Ach[tid][j] * Gfull[i*20 + j];
            ssq += Ai * inner;
        }
        float mean = s1 / (float)NK;
        float var  = ssq / (float)NK - mean * mean;
        float sc = g[tid] * rsqrtf(var + 1e-5f);
        ws[WS_BN1_SS + tid] = sc;
        ws[WS_BN1_SS + 64 + tid] = b[tid] - mean * sc;
    }
}

// load e[16] + q[3] for one element
__device__ __forceinline__ void build_eq(
    const float* __restrict__ e_in, const float* __restrict__ o_pr,
    const float* __restrict__ lpw1, const float* __restrict__ lpb1,
    const float* __restrict__ wsro, int id, float* e, float* q)
{
    const float4* ep = (const float4*)(e_in + (size_t)id * 16);
    #pragma unroll
    for (int i = 0; i < 4; ++i) {
        float4 v = ep[i];
        e[4*i] = v.x; e[4*i+1] = v.y; e[4*i+2] = v.z; e[4*i+3] = v.w;
    }
    float pr0 = o_pr[id*3+0], pr1 = o_pr[id*3+1], pr2 = o_pr[id*3+2];
    float v0 = lpb1[0] + lpw1[0]*pr0 + lpw1[1]*pr1 + lpw1[2]*pr2;
    float v1 = lpb1[1] + lpw1[3]*pr0 + lpw1[4]*pr1 + lpw1[5]*pr2;
    float v2 = lpb1[2] + lpw1[6]*pr0 + lpw1[7]*pr1 + lpw1[8]*pr2;
    q[0] = fmaxf(v0*wsro[WS_BNP_SS+0] + wsro[WS_BNP_SS+3], 0.f);
    q[1] = fmaxf(v1*wsro[WS_BNP_SS+1] + wsro[WS_BNP_SS+4], 0.f);
    q[2] = fmaxf(v2*wsro[WS_BNP_SS+2] + wsro[WS_BNP_SS+5], 0.f);
}

// stage2: t2 = c2 @ relu(bn1(h1)); 4 channels per c-iter with split
// accumulators => 8 independent FMA chains per element (latency -> issue bound)
__global__ __launch_bounds__(256) void k_stage2(
    const float* __restrict__ wsro, const float* __restrict__ out_ro,
    const float* __restrict__ lpw1, const float* __restrict__ lpb1,
    const float* __restrict__ c1w, float* __restrict__ ws)
{
    float tsum[8] = {0,0,0,0,0,0,0,0}, tssq[8] = {0,0,0,0,0,0,0,0};
    const float* e_in = wsro + WS_E;
    const float* o_pr = out_ro + OUT_PR;
    float* t2 = ws + WS_T2;
    int id = blockIdx.x * 256 + threadIdx.x;
    #pragma unroll 1
    for (int it = 0; it < 2; ++it, id += NK_STRIDE) {
        float e[16], q[3];
        build_eq(e_in, o_pr, lpw1, lpb1, wsro, id, e, q);
        float t2a[8] = {0,0,0,0,0,0,0,0};
        #pragma unroll 1
        for (int c = 0; c < 64; c += 4) {
            float h[4];
            #pragma unroll
            for (int r = 0; r < 4; ++r) {
                const float* wr = c1w + (c + r) * 32;
                const float4 fr = *(const float4*)(wsro + WS_C1F + (c + r) * 4);
                float a0 = fr.w + fr.x*q[0] + fr.y*q[1] + fr.z*q[2];
                float a1 = 0.f;
                #pragma unroll
                for (int k = 0; k < 16; k += 2) {
                    a0 += wr[k] * e[k];
                    a1 += wr[k+1] * e[k+1];
                }
                h[r] = fmaxf((a0 + a1) * wsro[WS_BN1_SS + c + r] + wsro[WS_BN1_SS + 64 + c + r], 0.f);
            }
            #pragma unroll
            for (int r = 0; r < 4; ++r) {
                const float4 cr0 = *(const float4*)(wsro + WS_C2T + (c + r) * 8);
                const float4 cr1 = *(const float4*)(wsro + WS_C2T + (c + r) * 8 + 4);
                float hh = h[r];
                t2a[0] += hh * cr0.x; t2a[1] += hh * cr0.y;
                t2a[2] += hh * cr0.z; t2a[3] += hh * cr0.w;
                t2a[4] += hh * cr1.x; t2a[5] += hh * cr1.y;
                t2a[6] += hh * cr1.z; t2a[7] += hh * cr1.w;
            }
        }
        float4* t2p = (float4*)(t2 + (size_t)id * 8);
        t2p[0] = make_float4(t2a[0], t2a[1], t2a[2], t2a[3]);
        t2p[1] = make_float4(t2a[4], t2a[5], t2a[6], t2a[7]);
        #pragma unroll
        for (int c2 = 0; c2 < 8; ++c2) { tsum[c2] += t2a[c2]; tssq[c2] += t2a[c2] * t2a[c2]; }
    }
    __shared__ float sacc[16];
    if (threadIdx.x < 16) sacc[threadIdx.x] = 0.f;
    __syncthreads();
    #pragma unroll
    for (int c2 = 0; c2 < 8; ++c2) {
        float s = tsum[c2], s2 = tssq[c2];
        #pragma unroll
        for (int off = 32; off; off >>= 1) { s += __shfl_xor(s, off); s2 += __shfl_xor(s2, off); }
        if ((threadIdx.x & 63) == 0) { atomicAdd(&sacc[c2], s); atomicAdd(&sacc[8 + c2], s2); }
    }
    __syncthreads();
    if (threadIdx.x < 16) atomicAdd(&ws[WS_BN2_RAW + threadIdx.x], sacc[threadIdx.x]);
}

__global__ void k_fin_bn2(float* __restrict__ ws, const float* __restrict__ g, const float* __restrict__ b)
{
    int c = threadIdx.x;
    if (c < 8) {
        float mean = ws[WS_BN2_RAW + c] / (float)NK;
        float var  = ws[WS_BN2_RAW + 8 + c] / (float)NK - mean * mean;
        float sc = g[c] * rsqrtf(var + 1e-5f);
        ws[WS_BN2_SS + c] = sc;
        ws[WS_BN2_SS + 8 + c] = b[c] - mean * sc;
    }
}

// 1 wave per point (4 points / 256-thread block). Thread = channel c;
// k-loop of 16; x_out written directly (no cross-thread reduction).
__global__ __launch_bounds__(256) void k_final(
    const int* __restrict__ knn, const float* __restrict__ wsro,
    const float* __restrict__ c3w, const float* __restrict__ c3b,
    const float* __restrict__ lpw1, const float* __restrict__ lpb1,
    const float* __restrict__ lpw2, const float* __restrict__ lpb2,
    float* __restrict__ out)
{
    int t = threadIdx.x;
    int sub = t >> 6, tl = t & 63;
    int n = blockIdx.x * 4 + sub;
    __shared__ float h2s[4][16][8], ssm[4][16][8], wls[4][16][8], pes[4][16][3], prs[4][48];
    __shared__ int idxs[4][16];
    const float* t2   = wsro + WS_T2;
    const float* o_pr = out + OUT_PR;
    const float* xrow = wsro + WS_XROW;
    if (tl < 16) idxs[sub][tl] = knn[n * 16 + tl];
    if (tl < 48) prs[sub][tl] = o_pr[(size_t)n * 48 + tl];
    {
        int k = tl >> 3, c2 = tl & 7;
        float v0 = t2[(size_t)n * 128 + tl];
        float v1 = t2[(size_t)n * 128 + 64 + tl];
        h2s[sub][k][c2]     = fmaxf(v0 * wsro[WS_BN2_SS + c2] + wsro[WS_BN2_SS + 8 + c2], 0.f);
        h2s[sub][8 + k][c2] = fmaxf(v1 * wsro[WS_BN2_SS + c2] + wsro[WS_BN2_SS + 8 + c2], 0.f);
    }
    __syncthreads();
    if (tl < 48) {
        int k = tl / 3, d = tl % 3;
        float pe = lpb1[d] + lpw1[d*3+0]*prs[sub][k*3+0] + lpw1[d*3+1]*prs[sub][k*3+1] + lpw1[d*3+2]*prs[sub][k*3+2];
        pes[sub][k][d] = fmaxf(pe * wsro[WS_BNP_SS + d] + wsro[WS_BNP_SS + 3 + d], 0.f);
        // second half of pes (k=16..? no: 48 covers k=0..15,d — 16*3=48, done)
    }
    {
        int k = tl >> 3, cc = tl & 7;
        float s0 = c3b[cc], s1 = c3b[cc];
        #pragma unroll
        for (int q = 0; q < 8; ++q) {
            s0 += h2s[sub][k][q]     * c3w[cc * 8 + q];
            s1 += h2s[sub][8 + k][q] * c3w[cc * 8 + q];
        }
        ssm[sub][k][cc] = s0;
        ssm[sub][8 + k][cc] = s1;
    }
    __syncthreads();
    if (tl < 8) {
        float m = -1e30f;
        for (int k = 0; k < 16; ++k) m = fmaxf(m, ssm[sub][k][tl]);
        float sum = 0.f;
        for (int k = 0; k < 16; ++k) { float ev = __expf(ssm[sub][k][tl] - m); wls[sub][k][tl] = ev; sum += ev; }
        float inv = 1.f / sum;
        for (int k = 0; k < 16; ++k) wls[sub][k][tl] *= inv;
    }
    __syncthreads();
    int c = tl;
    float w20 = lpw2[c*3], w21 = lpw2[c*3+1], w22 = lpw2[c*3+2], bc = lpb2[c];
    float acc = 0.f;
    float* out_xk = out + OUT_XK + (size_t)n * 1024;
    #pragma unroll 1
    for (int k = 0; k < 16; ++k) {
        float xv = xrow[(size_t)idxs[sub][k] * 64 + c];
        float pemb = bc + w20 * pes[sub][k][0] + w21 * pes[sub][k][1] + w22 * pes[sub][k][2];
        float val = (xv + pemb) * wls[sub][k][c & 7];
        out_xk[k * 64 + c] = val;
        acc += val;
    }
    out[(size_t)n * 64 + c] = acc;
}

// ---------------- launch ----------------
extern "C" void kernel_launch(void* const* d_in, const int* in_sizes, int n_in,
                              void* d_out, int out_size, void* d_ws, size_t ws_size,
                              hipStream_t stream)
{
    (void)in_sizes; (void)n_in; (void)out_size; (void)ws_size;
    const float* p    = (const float*)d_in[0];
    const float* x    = (const float*)d_in[1];
    const int*   knn  = (const int*)  d_in[2];
    const float* w1   = (const float*)d_in[3];
    const float* b1   = (const float*)d_in[4];
    const float* bw   = (const float*)d_in[5];
    const float* bb   = (const float*)d_in[6];
    const float* lpw1 = (const float*)d_in[7];
    const float* lpb1 = (const float*)d_in[8];
    const float* bnpg = (const float*)d_in[9];
    const float* bnpb = (const float*)d_in[10];
    const float* lpw2 = (const float*)d_in[11];
    const float* lpb2 = (const float*)d_in[12];
    const float* c1w  = (const float*)d_in[13];
    const float* bn1g = (const float*)d_in[14];
    const float* bn1b = (const float*)d_in[15];
    const float* c2w  = (const float*)d_in[16];
    const float* bn2g = (const float*)d_in[17];
    const float* bn2b = (const float*)d_in[18];
    const float* c3w  = (const float*)d_in[19];
    const float* c3b  = (const float*)d_in[20];
    const float* w3   = (const float*)d_in[21];
    const float* b3   = (const float*)d_in[22];
    float* out = (float*)d_out;
    float* ws  = (float*)d_ws;

    (void)hipMemsetAsync(ws, 0, 6016 * sizeof(float), stream);
    k_pre   <<<(NPTS + 255) / 256, 256, 0, stream>>>(x, w3, b3, w1, b1, ws);
    k_sym   <<<9, 256, 0, stream>>>(bw, ws);
    k_pstats<<<GRID_NK, 256, 0, stream>>>(p, knn, lpw1, lpb1, ws, out);
    k_fin_bnp<<<1, 128, 0, stream>>>(ws, bnpg, bnpb, lpw2, lpb2);
    k_fold  <<<1, 64, 0, stream>>>(c1w, c2w, ws);
    k_stage0<<<GRID_NK, 256, 0, stream>>>(out + OUT_PR, knn, w1, bb, lpw1, lpb1, ws, ws);
    k_fin_bn1<<<1, 256, 0, stream>>>(c1w, bn1g, bn1b, ws);
    k_stage2<<<GRID_NK, 256, 0, stream>>>(ws, out, lpw1, lpb1, c1w, ws);
    k_fin_bn2<<<1, 64, 0, stream>>>(ws, bn2g, bn2b);
    k_final <<<NPTS / 4, 256, 0, stream>>>(knn, ws, c3w, c3b, lpw1, lpb1, lpw2, lpb2, out);
}